// Round 1
// baseline (3575.891 us; speedup 1.0000x reference)
//
#include <hip/hip_runtime.h>
#include <hip/hip_bf16.h>
#include <math.h>

constexpr int N_NODES = 50000;
constexpr int N_EDGES = 800000;
constexpr int D  = 128;
constexpr int ED = 64;

static __device__ __forceinline__ float allsum64(float v){
#pragma unroll
  for(int off=32; off>=1; off>>=1) v += __shfl_xor(v, off, 64);
  return v;
}

static __device__ __forceinline__ unsigned fmap(float f){
  unsigned u = __float_as_uint(f);
  return (u & 0x80000000u) ? ~u : (u | 0x80000000u);
}

template<typename T> __device__ __forceinline__ T cvt_out(float v);
template<> __device__ __forceinline__ float cvt_out<float>(float v){ return v; }
template<> __device__ __forceinline__ __hip_bfloat16 cvt_out<__hip_bfloat16>(float v){ return __float2bfloat16(v); }

// ---------------- degree count ----------------
__global__ void k_deg(const int* __restrict__ src, int* __restrict__ deg){
  int i = blockIdx.x*256 + threadIdx.x;
  if(i < N_EDGES) atomicAdd(&deg[src[i]], 1);
}

// ---------------- x_in = x + deg_emb ; h = LN(x_in) ----------------
__global__ __launch_bounds__(256) void k_node_prep(
    const float* __restrict__ x, const int* __restrict__ deg,
    const float* __restrict__ deg_emb, const float* __restrict__ g,
    const float* __restrict__ b, float* __restrict__ xin, float* __restrict__ h){
  int node = blockIdx.x*4 + (threadIdx.x>>6);
  int lane = threadIdx.x & 63;
  if(node >= N_NODES) return;
  int dg = deg[node]; dg = dg > 511 ? 511 : dg;
  const float* xr = x + (size_t)node*D;
  const float* er = deg_emb + (size_t)dg*D;
  float a0 = xr[lane]    + er[lane];
  float a1 = xr[lane+64] + er[lane+64];
  float* xo = xin + (size_t)node*D;
  xo[lane] = a0; xo[lane+64] = a1;
  float s  = allsum64(a0+a1);
  float s2 = allsum64(a0*a0 + a1*a1);
  float mean = s * (1.f/128.f);
  float var  = s2 * (1.f/128.f) - mean*mean;
  float rs = rsqrtf(var + 1e-5f);
  float* ho = h + (size_t)node*D;
  ho[lane]    = (a0-mean)*rs*g[lane]    + b[lane];
  ho[lane+64] = (a1-mean)*rs*g[lane+64] + b[lane+64];
}

// ---------------- pack Wq|Wk|Wv|Wskip into [128][512] ----------------
__global__ void k_pack(const float* __restrict__ Wq, const float* __restrict__ Wk,
                       const float* __restrict__ Wv, const float* __restrict__ Ws,
                       const float* __restrict__ bq, const float* __restrict__ bk,
                       const float* __restrict__ bv, const float* __restrict__ bs,
                       float* __restrict__ Wcat, float* __restrict__ bcat){
  int idx = blockIdx.x*256 + threadIdx.x;
  if(idx < D*4*D){
    int i = idx >> 9, j = idx & 511;
    int sel = j >> 7, jj = j & 127;
    const float* W = sel==0?Wq: sel==1?Wk: sel==2?Wv:Ws;
    Wcat[idx] = W[i*D + jj];
  } else if(idx < D*4*D + 4*D){
    int j = idx - D*4*D;
    int sel = j>>7, jj = j&127;
    const float* B = sel==0?bq: sel==1?bk: sel==2?bv:bs;
    bcat[j] = B[jj];
  }
}

// ---------------- generic f32 SGEMM: C = act(A@B + bias) (+Src) ----------------
// BM=64 BN=64 BK=32, 256 threads, 4x4 per thread. ACT: 0=none 1=gelu(exact)
template<int ACT, bool SRCADD, typename OutT>
__global__ __launch_bounds__(256) void k_sgemm(
    const float* __restrict__ A, const float* __restrict__ B,
    const float* __restrict__ bias, const float* __restrict__ Src,
    OutT* __restrict__ C, int M, int K, int Nc){
  __shared__ float As[64*33];
  __shared__ float Bs[32*68];
  const int tid = threadIdx.x;
  const int tx = tid & 15, ty = tid >> 4;
  const int bm0 = blockIdx.x * 64;
  const int bn0 = blockIdx.y * 64;
  const int arow = tid >> 2, acol = (tid & 3)*8;
  const int brow = tid >> 3, bcol = (tid & 7)*8;
  float acc[4][4] = {};
  for(int k0 = 0; k0 < K; k0 += 32){
    int gr = bm0 + arow;
    float* as = &As[arow*33 + acol];
    if(gr < M){
      const float* ap = A + (size_t)gr*K + k0 + acol;
      float4 v0 = *(const float4*)ap;
      float4 v1 = *(const float4*)(ap+4);
      as[0]=v0.x; as[1]=v0.y; as[2]=v0.z; as[3]=v0.w;
      as[4]=v1.x; as[5]=v1.y; as[6]=v1.z; as[7]=v1.w;
    } else {
#pragma unroll
      for(int i=0;i<8;i++) as[i]=0.f;
    }
    {
      const float* bp = B + (size_t)(k0+brow)*Nc + bn0 + bcol;
      float4 v0 = *(const float4*)bp;
      float4 v1 = *(const float4*)(bp+4);
      *(float4*)&Bs[brow*68 + bcol]   = v0;
      *(float4*)&Bs[brow*68 + bcol+4] = v1;
    }
    __syncthreads();
#pragma unroll
    for(int k=0;k<32;k++){
      float a0 = As[(ty*4+0)*33 + k];
      float a1 = As[(ty*4+1)*33 + k];
      float a2 = As[(ty*4+2)*33 + k];
      float a3 = As[(ty*4+3)*33 + k];
      float4 bv = *(float4*)&Bs[k*68 + tx*4];
      acc[0][0] += a0*bv.x; acc[0][1] += a0*bv.y; acc[0][2] += a0*bv.z; acc[0][3] += a0*bv.w;
      acc[1][0] += a1*bv.x; acc[1][1] += a1*bv.y; acc[1][2] += a1*bv.z; acc[1][3] += a1*bv.w;
      acc[2][0] += a2*bv.x; acc[2][1] += a2*bv.y; acc[2][2] += a2*bv.z; acc[2][3] += a2*bv.w;
      acc[3][0] += a3*bv.x; acc[3][1] += a3*bv.y; acc[3][2] += a3*bv.z; acc[3][3] += a3*bv.w;
    }
    __syncthreads();
  }
  const int c0 = bn0 + tx*4;
#pragma unroll
  for(int i=0;i<4;i++){
    int r = bm0 + ty*4 + i;
    if(r >= M) continue;
#pragma unroll
    for(int j=0;j<4;j++){
      float v = acc[i][j] + bias[c0+j];
      if(ACT == 1) v = v * 0.5f * (1.f + erff(v * 0.70710678118f));
      if(SRCADD) v += Src[(size_t)r*Nc + c0 + j];
      C[(size_t)r*Nc + c0 + j] = cvt_out<OutT>(v);
    }
  }
}

// ---------------- attention pass A: alpha + segment max ----------------
__global__ __launch_bounds__(256) void k_alpha(
    const int* __restrict__ src, const int* __restrict__ dst,
    const float* __restrict__ qkvs, const __hip_bfloat16* __restrict__ eproj,
    float* __restrict__ alpha, unsigned* __restrict__ amaxu){
  int e = blockIdx.x*4 + (threadIdx.x>>6);
  int lane = threadIdx.x & 63;
  int s = src[e], d = dst[e];
  const float* qrow = qkvs + (size_t)d*512;
  const float* krow = qkvs + (size_t)s*512 + 128;
  const __hip_bfloat16* er = eproj + (size_t)e*128;
  float e0 = __bfloat162float(er[lane]);
  float e1 = __bfloat162float(er[lane+64]);
  float p0 = qrow[lane]    * (krow[lane]    + e0);
  float p1 = qrow[lane+64] * (krow[lane+64] + e1);
#pragma unroll
  for(int off=8; off>=1; off>>=1){
    p0 += __shfl_xor(p0, off, 64);
    p1 += __shfl_xor(p1, off, 64);
  }
  if((lane & 15) == 0){
    int g = lane >> 4;
    float a0 = p0 * 0.25f;   // / sqrt(16)
    float a1 = p1 * 0.25f;
    alpha[(size_t)e*8 + g]     = a0;
    alpha[(size_t)e*8 + 4 + g] = a1;
    atomicMax(&amaxu[(size_t)d*8 + g],     fmap(a0));
    atomicMax(&amaxu[(size_t)d*8 + 4 + g], fmap(a1));
  }
}

// ---------------- decode mapped max; empty segment -> 0 ----------------
__global__ void k_amax_fin(unsigned* __restrict__ amaxu){
  int i = blockIdx.x*256 + threadIdx.x;
  if(i >= N_NODES*8) return;
  unsigned u = amaxu[i];
  float f;
  if(u == 0u) f = 0.f;
  else {
    unsigned bits = (u & 0x80000000u) ? (u & 0x7FFFFFFFu) : ~u;
    f = __uint_as_float(bits);
    if(!isfinite(f)) f = 0.f;
  }
  ((float*)amaxu)[i] = f;
}

// ---------------- pass B: ex = exp(alpha - amax[dst]); denom += ex ----------------
__global__ void k_ex(const int* __restrict__ dst, float* __restrict__ alpha,
                     const float* __restrict__ amax, float* __restrict__ denom){
  int t = blockIdx.x*256 + threadIdx.x;   // E*8 exact
  int e = t >> 3, hh = t & 7;
  int d = dst[e];
  float exv = expf(alpha[t] - amax[(size_t)d*8 + hh]);
  alpha[t] = exv;
  atomicAdd(&denom[(size_t)d*8 + hh], exv);
}

// ---------------- pass C: scatter (v[src]+e)*w into attnout ----------------
__global__ __launch_bounds__(256) void k_msg(
    const int* __restrict__ src, const int* __restrict__ dst,
    const float* __restrict__ qkvs, const __hip_bfloat16* __restrict__ eproj,
    const float* __restrict__ ex, const float* __restrict__ denom,
    float* __restrict__ attnout){
  int e = blockIdx.x*4 + (threadIdx.x>>6);
  int lane = threadIdx.x & 63;
  int s = src[e], d = dst[e];
  int g = lane >> 4;
  float w0 = ex[(size_t)e*8 + g]     / (denom[(size_t)d*8 + g]     + 1e-16f);
  float w1 = ex[(size_t)e*8 + 4 + g] / (denom[(size_t)d*8 + 4 + g] + 1e-16f);
  const float* vrow = qkvs + (size_t)s*512 + 256;
  const __hip_bfloat16* er = eproj + (size_t)e*128;
  float m0 = (vrow[lane]    + __bfloat162float(er[lane]))    * w0;
  float m1 = (vrow[lane+64] + __bfloat162float(er[lane+64])) * w1;
  atomicAdd(&attnout[(size_t)d*128 + lane],      m0);
  atomicAdd(&attnout[(size_t)d*128 + 64 + lane], m1);
}

// ---------------- x_attn = x_in + attnout + skip ; hf = LN(x_attn) ----------------
__global__ __launch_bounds__(256) void k_post_attn(
    const float* __restrict__ xin, const float* __restrict__ qkvs,
    const float* __restrict__ g, const float* __restrict__ b,
    float* __restrict__ xattn /* in: attnout, out: x_attn in place */,
    float* __restrict__ hf){
  int node = blockIdx.x*4 + (threadIdx.x>>6);
  int lane = threadIdx.x & 63;
  if(node >= N_NODES) return;
  const float* skip = qkvs + (size_t)node*512 + 384;
  size_t base = (size_t)node*D;
  float a0 = xin[base+lane]    + xattn[base+lane]    + skip[lane];
  float a1 = xin[base+lane+64] + xattn[base+lane+64] + skip[lane+64];
  xattn[base+lane] = a0; xattn[base+lane+64] = a1;
  float s  = allsum64(a0+a1);
  float s2 = allsum64(a0*a0 + a1*a1);
  float mean = s * (1.f/128.f);
  float var  = s2 * (1.f/128.f) - mean*mean;
  float rs = rsqrtf(var + 1e-5f);
  hf[base+lane]    = (a0-mean)*rs*g[lane]    + b[lane];
  hf[base+lane+64] = (a1-mean)*rs*g[lane+64] + b[lane+64];
}

// ---------------- xn = LN(x_new) with eu_ln ----------------
__global__ __launch_bounds__(256) void k_xn(
    const float* __restrict__ xnew, const float* __restrict__ g,
    const float* __restrict__ b, float* __restrict__ xn){
  int node = blockIdx.x*4 + (threadIdx.x>>6);
  int lane = threadIdx.x & 63;
  if(node >= N_NODES) return;
  size_t base = (size_t)node*D;
  float a0 = xnew[base+lane];
  float a1 = xnew[base+lane+64];
  float s  = allsum64(a0+a1);
  float s2 = allsum64(a0*a0 + a1*a1);
  float mean = s * (1.f/128.f);
  float var  = s2 * (1.f/128.f) - mean*mean;
  float rs = rsqrtf(var + 1e-5f);
  xn[base+lane]    = (a0-mean)*rs*g[lane]    + b[lane];
  xn[base+lane+64] = (a1-mean)*rs*g[lane+64] + b[lane+64];
}

// ---------------- EdgeUpdate: 32 edges/block, m[320] @ Wm[320x128] ----------------
__global__ __launch_bounds__(256) void k_edge_update(
    const int* __restrict__ src, const int* __restrict__ dst,
    const float* __restrict__ xn, const float* __restrict__ ea,
    const float* __restrict__ Wm, const float* __restrict__ bm,
    const float* __restrict__ eg, const float* __restrict__ ebv,
    float* __restrict__ out){
  __shared__ float mA[32*321];    // staged A tile (also reused as raw[32*130])
  __shared__ float wB[32*128];    // Wm K-chunk
  const int tid = threadIdx.x;
  const int e0 = blockIdx.x * 32;
  // stage m rows: [xn[src] | xn[dst] | edge_attr]
  {
    int r = tid >> 3, j = tid & 7;
    int e = e0 + r;
    int s = src[e], dd = dst[e];
    const float* p1 = xn + (size_t)s*128;
    const float* p2 = xn + (size_t)dd*128;
    const float* p3 = ea + (size_t)e*64;
    for(int i=0;i<40;i++){
      int k = j*40 + i;
      float v = (k < 128) ? p1[k] : ((k < 256) ? p2[k-128] : p3[k-256]);
      mA[r*321 + k] = v;
    }
  }
  const int tx = tid & 31, ty = tid >> 5;   // outputs: rows ty*4..+3 (32), cols tx*4..+3 (128)
  float acc[4][4] = {};
  for(int kc=0;kc<10;kc++){
    {
      int row = tid >> 3, c0 = (tid & 7)*16;
      const float* wp = Wm + (size_t)(kc*32+row)*128 + c0;
      float4 v0=*(const float4*)(wp),   v1=*(const float4*)(wp+4);
      float4 v2=*(const float4*)(wp+8), v3=*(const float4*)(wp+12);
      *(float4*)&wB[row*128+c0]    = v0;
      *(float4*)&wB[row*128+c0+4]  = v1;
      *(float4*)&wB[row*128+c0+8]  = v2;
      *(float4*)&wB[row*128+c0+12] = v3;
    }
    __syncthreads();
#pragma unroll
    for(int k=0;k<32;k++){
      int kk = kc*32 + k;
      float a0 = mA[(ty*4+0)*321 + kk];
      float a1 = mA[(ty*4+1)*321 + kk];
      float a2 = mA[(ty*4+2)*321 + kk];
      float a3 = mA[(ty*4+3)*321 + kk];
      float4 bv = *(float4*)&wB[k*128 + tx*4];
      acc[0][0] += a0*bv.x; acc[0][1] += a0*bv.y; acc[0][2] += a0*bv.z; acc[0][3] += a0*bv.w;
      acc[1][0] += a1*bv.x; acc[1][1] += a1*bv.y; acc[1][2] += a1*bv.z; acc[1][3] += a1*bv.w;
      acc[2][0] += a2*bv.x; acc[2][1] += a2*bv.y; acc[2][2] += a2*bv.z; acc[2][3] += a2*bv.w;
      acc[3][0] += a3*bv.x; acc[3][1] += a3*bv.y; acc[3][2] += a3*bv.z; acc[3][3] += a3*bv.w;
    }
    __syncthreads();
  }
  // relu + bias -> raw staged in LDS (stride 130 to dodge bank conflicts)
  float* raw = mA;
#pragma unroll
  for(int i=0;i<4;i++)
#pragma unroll
    for(int j=0;j<4;j++)
      raw[(ty*4+i)*130 + tx*4+j] = fmaxf(0.f, acc[i][j] + bm[tx*4+j]);
  __syncthreads();
  // per-edge LN over 64 dims of ea + sigmoid(gate)*delta
  {
    int r = tid >> 3, j = tid & 7;
    int e = e0 + r;
    const float* p3 = ea + (size_t)e*64;
    float vals[8];
    float s1 = 0.f, s2 = 0.f;
#pragma unroll
    for(int i=0;i<8;i++){
      int dcol = j*8 + i;
      float delta = raw[r*130 + dcol];
      float gate  = raw[r*130 + 64 + dcol];
      float v = p3[dcol] + delta / (1.f + expf(-gate));
      vals[i] = v; s1 += v; s2 += v*v;
    }
#pragma unroll
    for(int off=4; off>=1; off>>=1){
      s1 += __shfl_xor(s1, off, 64);
      s2 += __shfl_xor(s2, off, 64);
    }
    float mean = s1 * (1.f/64.f);
    float var  = s2 * (1.f/64.f) - mean*mean;
    float rs = rsqrtf(var + 1e-5f);
#pragma unroll
    for(int i=0;i<8;i++){
      int dcol = j*8 + i;
      out[(size_t)e*64 + dcol] = (vals[i]-mean)*rs*eg[dcol] + ebv[dcol];
    }
  }
}

extern "C" void kernel_launch(void* const* d_in, const int* in_sizes, int n_in,
                              void* d_out, int out_size, void* d_ws, size_t ws_size,
                              hipStream_t stream){
  const float* x       = (const float*)d_in[0];
  const int*   eidx    = (const int*)d_in[1];
  const float* eattr   = (const float*)d_in[2];
  const float* deg_emb = (const float*)d_in[3];
  const float* ln_g = (const float*)d_in[4];
  const float* ln_b = (const float*)d_in[5];
  const float* Wq = (const float*)d_in[6];  const float* bq = (const float*)d_in[7];
  const float* Wk = (const float*)d_in[8];  const float* bk = (const float*)d_in[9];
  const float* Wv = (const float*)d_in[10]; const float* bv = (const float*)d_in[11];
  const float* We = (const float*)d_in[12]; const float* be = (const float*)d_in[13];
  const float* Ws = (const float*)d_in[14]; const float* bs = (const float*)d_in[15];
  const float* W1 = (const float*)d_in[16]; const float* b1 = (const float*)d_in[17];
  const float* W2 = (const float*)d_in[18]; const float* b2 = (const float*)d_in[19];
  const float* eug = (const float*)d_in[20]; const float* eub = (const float*)d_in[21];
  const float* Wm = (const float*)d_in[22]; const float* bm = (const float*)d_in[23];
  const float* eg = (const float*)d_in[24]; const float* eb = (const float*)d_in[25];
  (void)in_sizes; (void)n_in; (void)out_size; (void)ws_size;

  const int* src = eidx;
  const int* dst = eidx + N_EDGES;

  float* ws = (float*)d_ws;
  size_t o = 0;
  auto alloc = [&](size_t n){ size_t r = o; o += (n + 63) & ~(size_t)63; return r; };
  size_t o_deg   = alloc(N_NODES);                 // int
  size_t o_amax  = alloc((size_t)N_NODES*8);       // uint -> float in place
  size_t o_denom = alloc((size_t)N_NODES*8);
  size_t o_attn  = alloc((size_t)N_NODES*D);       // attnout -> x_attn in place
  size_t zero_f  = o;                              // memset region end
  size_t o_xin   = alloc((size_t)N_NODES*D);       // x_in -> xn later
  size_t o_h     = alloc((size_t)N_NODES*D);       // h -> hf later
  size_t o_qkvs  = alloc((size_t)N_NODES*4*D);     // q|k|v|skip -> t1 later
  size_t o_alpha = alloc((size_t)N_EDGES*8);       // alpha -> ex in place
  size_t o_wcat  = alloc((size_t)D*4*D);
  size_t o_bcat  = alloc(4*D);

  float* xnew_out = (float*)d_out;                          // [N, 128]
  float* ea_out   = xnew_out + (size_t)N_NODES*D;           // [E, 64]
  // e-projection scratch (bf16) lives in d_out's ea region: E*128*2B == E*64*4B
  __hip_bfloat16* eproj = (__hip_bfloat16*)ea_out;

  hipMemsetAsync(d_ws, 0, zero_f*sizeof(float), stream);

  k_deg<<<(N_EDGES+255)/256, 256, 0, stream>>>(src, (int*)(ws+o_deg));
  k_node_prep<<<N_NODES/4, 256, 0, stream>>>(x, (int*)(ws+o_deg), deg_emb, ln_g, ln_b,
                                             ws+o_xin, ws+o_h);
  k_pack<<<(D*4*D + 4*D + 255)/256, 256, 0, stream>>>(Wq,Wk,Wv,Ws, bq,bk,bv,bs,
                                                      ws+o_wcat, ws+o_bcat);
  {
    dim3 g((N_NODES+63)/64, 8);
    k_sgemm<0,false,float><<<g,256,0,stream>>>(ws+o_h, ws+o_wcat, ws+o_bcat, nullptr,
                                               ws+o_qkvs, N_NODES, D, 4*D);
  }
  {
    dim3 g(N_EDGES/64, 2);
    k_sgemm<0,false,__hip_bfloat16><<<g,256,0,stream>>>(eattr, We, be, nullptr,
                                                        eproj, N_EDGES, ED, D);
  }
  k_alpha<<<N_EDGES/4, 256, 0, stream>>>(src, dst, ws+o_qkvs, eproj,
                                         ws+o_alpha, (unsigned*)(ws+o_amax));
  k_amax_fin<<<(N_NODES*8+255)/256, 256, 0, stream>>>((unsigned*)(ws+o_amax));
  k_ex<<<N_EDGES*8/256, 256, 0, stream>>>(dst, ws+o_alpha, ws+o_amax, ws+o_denom);
  k_msg<<<N_EDGES/4, 256, 0, stream>>>(src, dst, ws+o_qkvs, eproj,
                                       ws+o_alpha, ws+o_denom, ws+o_attn);
  k_post_attn<<<N_NODES/4, 256, 0, stream>>>(ws+o_xin, ws+o_qkvs, ln_g, ln_b,
                                             ws+o_attn, ws+o_h);
  {
    dim3 g((N_NODES+63)/64, 8);   // FFN1: t1 = gelu(hf@W1+b1) -> qkvs region
    k_sgemm<1,false,float><<<g,256,0,stream>>>(ws+o_h, W1, b1, nullptr,
                                               ws+o_qkvs, N_NODES, D, 4*D);
  }
  {
    dim3 g((N_NODES+63)/64, 2);   // FFN2: x_new = t1@W2+b2 + x_attn -> d_out
    k_sgemm<0,true,float><<<g,256,0,stream>>>(ws+o_qkvs, W2, b2, ws+o_attn,
                                              xnew_out, N_NODES, 4*D, D);
  }
  k_xn<<<N_NODES/4, 256, 0, stream>>>(xnew_out, eug, eub, ws+o_xin);
  k_edge_update<<<N_EDGES/32, 256, 0, stream>>>(src, dst, ws+o_xin, eattr,
                                                Wm, bm, eg, eb, ea_out);
}

// Round 3
// 1420.682 us; speedup vs baseline: 2.5170x; 2.5170x over previous
//
#include <hip/hip_runtime.h>
#include <hip/hip_bf16.h>
#include <math.h>

constexpr int N_NODES = 50000;
constexpr int N_EDGES = 800000;
constexpr int D  = 128;
constexpr int ED = 64;

typedef __attribute__((ext_vector_type(8))) short short8;
typedef __attribute__((ext_vector_type(4))) float f32x4;

static __device__ __forceinline__ float allsum64(float v){
#pragma unroll
  for(int off=32; off>=1; off>>=1) v += __shfl_xor(v, off, 64);
  return v;
}

static __device__ __forceinline__ unsigned fmap(float f){
  unsigned u = __float_as_uint(f);
  return (u & 0x80000000u) ? ~u : (u | 0x80000000u);
}

static __device__ __forceinline__ short bfs(float f){
  __hip_bfloat16 h = __float2bfloat16(f);
  return *reinterpret_cast<short*>(&h);
}
static __device__ __forceinline__ float bf2f(short s){
  __hip_bfloat16 h = *reinterpret_cast<__hip_bfloat16*>(&s);
  return __bfloat162float(h);
}

template<typename T> __device__ __forceinline__ T cvt_out(float v);
template<> __device__ __forceinline__ float cvt_out<float>(float v){ return v; }
template<> __device__ __forceinline__ __hip_bfloat16 cvt_out<__hip_bfloat16>(float v){ return __float2bfloat16(v); }

// ---------------- degree count ----------------
__global__ void k_deg(const int* __restrict__ src, int* __restrict__ deg){
  int i = blockIdx.x*256 + threadIdx.x;
  if(i < N_EDGES) atomicAdd(&deg[src[i]], 1);
}

// ---------------- x_in = x + deg_emb ; h = LN(x_in) ----------------
__global__ __launch_bounds__(256) void k_node_prep(
    const float* __restrict__ x, const int* __restrict__ deg,
    const float* __restrict__ deg_emb, const float* __restrict__ g,
    const float* __restrict__ b, float* __restrict__ xin, float* __restrict__ h){
  int node = blockIdx.x*4 + (threadIdx.x>>6);
  int lane = threadIdx.x & 63;
  if(node >= N_NODES) return;
  int dg = deg[node]; dg = dg > 511 ? 511 : dg;
  const float* xr = x + (size_t)node*D;
  const float* er = deg_emb + (size_t)dg*D;
  float a0 = xr[lane]    + er[lane];
  float a1 = xr[lane+64] + er[lane+64];
  float* xo = xin + (size_t)node*D;
  xo[lane] = a0; xo[lane+64] = a1;
  float s  = allsum64(a0+a1);
  float s2 = allsum64(a0*a0 + a1*a1);
  float mean = s * (1.f/128.f);
  float var  = s2 * (1.f/128.f) - mean*mean;
  float rs = rsqrtf(var + 1e-5f);
  float* ho = h + (size_t)node*D;
  ho[lane]    = (a0-mean)*rs*g[lane]    + b[lane];
  ho[lane+64] = (a1-mean)*rs*g[lane+64] + b[lane+64];
}

// ---------------- pack Wq|Wk|Wv|Wskip into [128][512] ----------------
__global__ void k_pack(const float* __restrict__ Wq, const float* __restrict__ Wk,
                       const float* __restrict__ Wv, const float* __restrict__ Ws,
                       const float* __restrict__ bq, const float* __restrict__ bk,
                       const float* __restrict__ bv, const float* __restrict__ bs,
                       float* __restrict__ Wcat, float* __restrict__ bcat){
  int idx = blockIdx.x*256 + threadIdx.x;
  if(idx < D*4*D){
    int i = idx >> 9, j = idx & 511;
    int sel = j >> 7, jj = j & 127;
    const float* W = sel==0?Wq: sel==1?Wk: sel==2?Wv:Ws;
    Wcat[idx] = W[i*D + jj];
  } else if(idx < D*4*D + 4*D){
    int j = idx - D*4*D;
    int sel = j>>7, jj = j&127;
    const float* B = sel==0?bq: sel==1?bk: sel==2?bv:bs;
    bcat[j] = B[jj];
  }
}

// ---------------- pack f32 W[K][128] -> bf16 MFMA-B-fragment order ----------------
// out[((kc*8+cf)*64 + lane)*8 + j] = W[kc*32 + (lane>>4)*8 + j][cf*16 + (lane&15)]
__global__ void k_packW(const float* __restrict__ W, __hip_bfloat16* __restrict__ out, int K){
  int idx = blockIdx.x*256 + threadIdx.x;
  if(idx >= K*128) return;
  int j  = idx & 7;
  int l  = (idx>>3) & 63;
  int cf = (idx>>9) & 7;
  int kc = idx >> 12;
  int k = kc*32 + ((l>>4)<<3) + j;
  int n = (cf<<4) + (l&15);
  out[idx] = __float2bfloat16(W[k*128 + n]);
}

// ---------------- generic f32 SGEMM: C = act(A@B + bias) (+Src) ----------------
template<int ACT, bool SRCADD, typename OutT>
__global__ __launch_bounds__(256) void k_sgemm(
    const float* __restrict__ A, const float* __restrict__ B,
    const float* __restrict__ bias, const float* __restrict__ Src,
    OutT* __restrict__ C, int M, int K, int Nc){
  __shared__ float As[64*33];
  __shared__ float Bs[32*68];
  const int tid = threadIdx.x;
  const int tx = tid & 15, ty = tid >> 4;
  const int bm0 = blockIdx.x * 64;
  const int bn0 = blockIdx.y * 64;
  const int arow = tid >> 2, acol = (tid & 3)*8;
  const int brow = tid >> 3, bcol = (tid & 7)*8;
  float acc[4][4] = {};
  for(int k0 = 0; k0 < K; k0 += 32){
    int gr = bm0 + arow;
    float* as = &As[arow*33 + acol];
    if(gr < M){
      const float* ap = A + (size_t)gr*K + k0 + acol;
      float4 v0 = *(const float4*)ap;
      float4 v1 = *(const float4*)(ap+4);
      as[0]=v0.x; as[1]=v0.y; as[2]=v0.z; as[3]=v0.w;
      as[4]=v1.x; as[5]=v1.y; as[6]=v1.z; as[7]=v1.w;
    } else {
#pragma unroll
      for(int i=0;i<8;i++) as[i]=0.f;
    }
    {
      const float* bp = B + (size_t)(k0+brow)*Nc + bn0 + bcol;
      float4 v0 = *(const float4*)bp;
      float4 v1 = *(const float4*)(bp+4);
      *(float4*)&Bs[brow*68 + bcol]   = v0;
      *(float4*)&Bs[brow*68 + bcol+4] = v1;
    }
    __syncthreads();
#pragma unroll
    for(int k=0;k<32;k++){
      float a0 = As[(ty*4+0)*33 + k];
      float a1 = As[(ty*4+1)*33 + k];
      float a2 = As[(ty*4+2)*33 + k];
      float a3 = As[(ty*4+3)*33 + k];
      float4 bv = *(float4*)&Bs[k*68 + tx*4];
      acc[0][0] += a0*bv.x; acc[0][1] += a0*bv.y; acc[0][2] += a0*bv.z; acc[0][3] += a0*bv.w;
      acc[1][0] += a1*bv.x; acc[1][1] += a1*bv.y; acc[1][2] += a1*bv.z; acc[1][3] += a1*bv.w;
      acc[2][0] += a2*bv.x; acc[2][1] += a2*bv.y; acc[2][2] += a2*bv.z; acc[2][3] += a2*bv.w;
      acc[3][0] += a3*bv.x; acc[3][1] += a3*bv.y; acc[3][2] += a3*bv.z; acc[3][3] += a3*bv.w;
    }
    __syncthreads();
  }
  const int c0 = bn0 + tx*4;
#pragma unroll
  for(int i=0;i<4;i++){
    int r = bm0 + ty*4 + i;
    if(r >= M) continue;
#pragma unroll
    for(int j=0;j<4;j++){
      float v = acc[i][j] + bias[c0+j];
      if(ACT == 1) v = v * 0.5f * (1.f + erff(v * 0.70710678118f));
      if(SRCADD) v += Src[(size_t)r*Nc + c0 + j];
      C[(size_t)r*Nc + c0 + j] = cvt_out<OutT>(v);
    }
  }
}

// ---------------- e-projection via MFMA: eproj = bf16(edge_attr @ We + be) ----------------
__global__ __launch_bounds__(256) void k_eproj_mfma(
    const float* __restrict__ eattr, const __hip_bfloat16* __restrict__ Wep,
    const float* __restrict__ be, __hip_bfloat16* __restrict__ out){
  const int tid = threadIdx.x, lane = tid & 63, wid = tid >> 6;
  const int l16 = lane & 15, lg = lane >> 4;
  const size_t row = (size_t)blockIdx.x*64 + wid*16;
  f32x4 acc[8] = {};
  const short8* Bg = ((const short8*)Wep) + lane;
  const float* ga = eattr + (row + l16)*64;
#pragma unroll
  for(int kc=0;kc<2;kc++){
    int cb = kc*32 + lg*8;
    float4 f0 = *(const float4*)(ga + cb);
    float4 f1 = *(const float4*)(ga + cb + 4);
    short8 a;
    a[0]=bfs(f0.x); a[1]=bfs(f0.y); a[2]=bfs(f0.z); a[3]=bfs(f0.w);
    a[4]=bfs(f1.x); a[5]=bfs(f1.y); a[6]=bfs(f1.z); a[7]=bfs(f1.w);
#pragma unroll
    for(int cf=0;cf<8;cf++){
      short8 b = Bg[(kc*8+cf)*64];
      acc[cf] = __builtin_amdgcn_mfma_f32_16x16x32_bf16(a, b, acc[cf], 0, 0, 0);
    }
  }
#pragma unroll
  for(int cf=0;cf<8;cf++){
    int col = cf*16 + l16;
    float bb = be[col];
#pragma unroll
    for(int r=0;r<4;r++){
      size_t ro = row + lg*4 + r;
      out[ro*128 + col] = __float2bfloat16(acc[cf][r] + bb);
    }
  }
}

// ---------------- attention pass A: alpha + segment max ----------------
__global__ __launch_bounds__(256) void k_alpha(
    const int* __restrict__ src, const int* __restrict__ dst,
    const float* __restrict__ qkvs, const __hip_bfloat16* __restrict__ eproj,
    float* __restrict__ alpha, unsigned* __restrict__ amaxu){
  int e = blockIdx.x*4 + (threadIdx.x>>6);
  int lane = threadIdx.x & 63;
  int s = src[e], d = dst[e];
  const float* qrow = qkvs + (size_t)d*512;
  const float* krow = qkvs + (size_t)s*512 + 128;
  const __hip_bfloat16* er = eproj + (size_t)e*128;
  float e0 = __bfloat162float(er[lane]);
  float e1 = __bfloat162float(er[lane+64]);
  float p0 = qrow[lane]    * (krow[lane]    + e0);
  float p1 = qrow[lane+64] * (krow[lane+64] + e1);
#pragma unroll
  for(int off=8; off>=1; off>>=1){
    p0 += __shfl_xor(p0, off, 64);
    p1 += __shfl_xor(p1, off, 64);
  }
  if((lane & 15) == 0){
    int g = lane >> 4;
    float a0 = p0 * 0.25f;
    float a1 = p1 * 0.25f;
    alpha[(size_t)e*8 + g]     = a0;
    alpha[(size_t)e*8 + 4 + g] = a1;
    atomicMax(&amaxu[(size_t)d*8 + g],     fmap(a0));
    atomicMax(&amaxu[(size_t)d*8 + 4 + g], fmap(a1));
  }
}

// ---------------- decode mapped max; empty segment -> 0 ----------------
__global__ void k_amax_fin(unsigned* __restrict__ amaxu){
  int i = blockIdx.x*256 + threadIdx.x;
  if(i >= N_NODES*8) return;
  unsigned u = amaxu[i];
  float f;
  if(u == 0u) f = 0.f;
  else {
    unsigned bits = (u & 0x80000000u) ? (u & 0x7FFFFFFFu) : ~u;
    f = __uint_as_float(bits);
    if(!isfinite(f)) f = 0.f;
  }
  ((float*)amaxu)[i] = f;
}

// ---------------- pass B: ex = exp(alpha - amax[dst]); denom += ex ----------------
__global__ void k_ex(const int* __restrict__ dst, float* __restrict__ alpha,
                     const float* __restrict__ amax, float* __restrict__ denom){
  int t = blockIdx.x*256 + threadIdx.x;
  int e = t >> 3, hh = t & 7;
  int d = dst[e];
  float exv = expf(alpha[t] - amax[(size_t)d*8 + hh]);
  alpha[t] = exv;
  atomicAdd(&denom[(size_t)d*8 + hh], exv);
}

// ---------------- pass C: scatter (v[src]+e)*w into attnout ----------------
__global__ __launch_bounds__(256) void k_msg(
    const int* __restrict__ src, const int* __restrict__ dst,
    const float* __restrict__ qkvs, const __hip_bfloat16* __restrict__ eproj,
    const float* __restrict__ ex, const float* __restrict__ denom,
    float* __restrict__ attnout){
  int e = blockIdx.x*4 + (threadIdx.x>>6);
  int lane = threadIdx.x & 63;
  int s = src[e], d = dst[e];
  int g = lane >> 4;
  float w0 = ex[(size_t)e*8 + g]     / (denom[(size_t)d*8 + g]     + 1e-16f);
  float w1 = ex[(size_t)e*8 + 4 + g] / (denom[(size_t)d*8 + 4 + g] + 1e-16f);
  const float* vrow = qkvs + (size_t)s*512 + 256;
  const __hip_bfloat16* er = eproj + (size_t)e*128;
  float m0 = (vrow[lane]    + __bfloat162float(er[lane]))    * w0;
  float m1 = (vrow[lane+64] + __bfloat162float(er[lane+64])) * w1;
  atomicAdd(&attnout[(size_t)d*128 + lane],      m0);
  atomicAdd(&attnout[(size_t)d*128 + 64 + lane], m1);
}

// ---------------- x_attn = x_in + attnout + skip ; hf = LN(x_attn) ----------------
__global__ __launch_bounds__(256) void k_post_attn(
    const float* __restrict__ xin, const float* __restrict__ qkvs,
    const float* __restrict__ g, const float* __restrict__ b,
    float* __restrict__ xattn, float* __restrict__ hf){
  int node = blockIdx.x*4 + (threadIdx.x>>6);
  int lane = threadIdx.x & 63;
  if(node >= N_NODES) return;
  const float* skip = qkvs + (size_t)node*512 + 384;
  size_t base = (size_t)node*D;
  float a0 = xin[base+lane]    + xattn[base+lane]    + skip[lane];
  float a1 = xin[base+lane+64] + xattn[base+lane+64] + skip[lane+64];
  xattn[base+lane] = a0; xattn[base+lane+64] = a1;
  float s  = allsum64(a0+a1);
  float s2 = allsum64(a0*a0 + a1*a1);
  float mean = s * (1.f/128.f);
  float var  = s2 * (1.f/128.f) - mean*mean;
  float rs = rsqrtf(var + 1e-5f);
  hf[base+lane]    = (a0-mean)*rs*g[lane]    + b[lane];
  hf[base+lane+64] = (a1-mean)*rs*g[lane+64] + b[lane+64];
}

// ---------------- xn = LN(x_new) with eu_ln (f32 out) ----------------
__global__ __launch_bounds__(256) void k_xn(
    const float* __restrict__ xnew, const float* __restrict__ g,
    const float* __restrict__ b, float* __restrict__ xn){
  int node = blockIdx.x*4 + (threadIdx.x>>6);
  int lane = threadIdx.x & 63;
  if(node >= N_NODES) return;
  size_t base = (size_t)node*D;
  float a0 = xnew[base+lane];
  float a1 = xnew[base+lane+64];
  float s  = allsum64(a0+a1);
  float s2 = allsum64(a0*a0 + a1*a1);
  float mean = s * (1.f/128.f);
  float var  = s2 * (1.f/128.f) - mean*mean;
  float rs = rsqrtf(var + 1e-5f);
  xn[base+lane]    = (a0-mean)*rs*g[lane]    + b[lane];
  xn[base+lane+64] = (a1-mean)*rs*g[lane+64] + b[lane+64];
}

// ---------------- EdgeUpdate via MFMA, LDS-free, split-precision A ----------------
// Wave = 16 edges x 128 cols. A built in-register from global gathers:
// kc 0-3 -> xn[src], 4-7 -> xn[dst], 8-9 -> ea. m = hi+lo bf16 split (2 MFMA).
// Epilogue: bias+relu, u = ea + sigmoid(gate)*delta, LN over 64 via 16-lane shfl.
__global__ __launch_bounds__(256) void k_edge_mfma2(
    const int* __restrict__ src, const int* __restrict__ dst,
    const float* __restrict__ xn, const float* __restrict__ ea,
    const __hip_bfloat16* __restrict__ Wmp, const float* __restrict__ bm,
    const float* __restrict__ eg, const float* __restrict__ ebv,
    float* __restrict__ out){
  const int tid = threadIdx.x, lane = tid & 63, wid = tid >> 6;
  const int l16 = lane & 15, lg = lane >> 4;
  const size_t e0 = (size_t)blockIdx.x*64 + wid*16;
  const size_t myrow = e0 + l16;
  const int s = src[myrow], d = dst[myrow];
  f32x4 acc[8] = {};
  const short8* Bg = ((const short8*)Wmp) + lane;
  const int ko = lg*8;

#pragma unroll
  for(int kc=0; kc<10; kc++){
    const float* ap;
    if(kc < 4)      ap = xn + (size_t)s*128 + kc*32 + ko;
    else if(kc < 8) ap = xn + (size_t)d*128 + (kc-4)*32 + ko;
    else            ap = ea + myrow*64 + (kc-8)*32 + ko;
    float4 f0 = *(const float4*)ap;
    float4 f1 = *(const float4*)(ap+4);
    float v[8] = {f0.x,f0.y,f0.z,f0.w,f1.x,f1.y,f1.z,f1.w};
    short8 ah, al;
#pragma unroll
    for(int j=0;j<8;j++){
      short h = bfs(v[j]);
      ah[j] = h;
      al[j] = bfs(v[j] - bf2f(h));
    }
#pragma unroll
    for(int cf=0;cf<8;cf++){
      short8 b = Bg[(kc*8+cf)*64];
      acc[cf] = __builtin_amdgcn_mfma_f32_16x16x32_bf16(ah, b, acc[cf], 0, 0, 0);
      acc[cf] = __builtin_amdgcn_mfma_f32_16x16x32_bf16(al, b, acc[cf], 0, 0, 0);
    }
  }

  // epilogue: lane owns rows e0 + lg*4 + r (r=0..3), cols {cf*16+l16, cf=0..3}
  float bmd[4], bmg[4], egc[4], ebc[4];
#pragma unroll
  for(int cf=0;cf<4;cf++){
    int col = cf*16 + l16;
    bmd[cf] = bm[col];
    bmg[cf] = bm[64+col];
    egc[cf] = eg[col];
    ebc[cf] = ebv[col];
  }
#pragma unroll
  for(int r=0;r<4;r++){
    size_t erow = e0 + lg*4 + r;
    float u[4];
    float s1 = 0.f, s2 = 0.f;
#pragma unroll
    for(int cf=0;cf<4;cf++){
      float dlt = fmaxf(0.f, acc[cf][r]   + bmd[cf]);
      float gt  = fmaxf(0.f, acc[cf+4][r] + bmg[cf]);
      float uu = ea[erow*64 + cf*16 + l16] + dlt / (1.f + expf(-gt));
      u[cf] = uu; s1 += uu; s2 += uu*uu;
    }
#pragma unroll
    for(int off=1; off<16; off<<=1){
      s1 += __shfl_xor(s1, off, 64);
      s2 += __shfl_xor(s2, off, 64);
    }
    float mean = s1 * (1.f/64.f);
    float var  = s2 * (1.f/64.f) - mean*mean;
    float rs = rsqrtf(var + 1e-5f);
#pragma unroll
    for(int cf=0;cf<4;cf++)
      out[erow*64 + cf*16 + l16] = (u[cf]-mean)*rs*egc[cf] + ebc[cf];
  }
}

extern "C" void kernel_launch(void* const* d_in, const int* in_sizes, int n_in,
                              void* d_out, int out_size, void* d_ws, size_t ws_size,
                              hipStream_t stream){
  const float* x       = (const float*)d_in[0];
  const int*   eidx    = (const int*)d_in[1];
  const float* eattr   = (const float*)d_in[2];
  const float* deg_emb = (const float*)d_in[3];
  const float* ln_g = (const float*)d_in[4];
  const float* ln_b = (const float*)d_in[5];
  const float* Wq = (const float*)d_in[6];  const float* bq = (const float*)d_in[7];
  const float* Wk = (const float*)d_in[8];  const float* bk = (const float*)d_in[9];
  const float* Wv = (const float*)d_in[10]; const float* bv = (const float*)d_in[11];
  const float* We = (const float*)d_in[12]; const float* be = (const float*)d_in[13];
  const float* Ws = (const float*)d_in[14]; const float* bs = (const float*)d_in[15];
  const float* W1 = (const float*)d_in[16]; const float* b1 = (const float*)d_in[17];
  const float* W2 = (const float*)d_in[18]; const float* b2 = (const float*)d_in[19];
  const float* eug = (const float*)d_in[20]; const float* eub = (const float*)d_in[21];
  const float* Wm = (const float*)d_in[22]; const float* bm = (const float*)d_in[23];
  const float* eg = (const float*)d_in[24]; const float* eb = (const float*)d_in[25];
  (void)in_sizes; (void)n_in; (void)out_size; (void)ws_size;

  const int* src = eidx;
  const int* dst = eidx + N_EDGES;

  float* ws = (float*)d_ws;
  size_t o = 0;
  auto alloc = [&](size_t n){ size_t r = o; o += (n + 63) & ~(size_t)63; return r; };
  size_t o_deg   = alloc(N_NODES);                 // int
  size_t o_amax  = alloc((size_t)N_NODES*8);       // uint -> float in place
  size_t o_denom = alloc((size_t)N_NODES*8);
  size_t o_attn  = alloc((size_t)N_NODES*D);       // attnout -> x_attn in place
  size_t zero_f  = o;                              // memset region end
  size_t o_xin   = alloc((size_t)N_NODES*D);       // x_in -> xn (f32) later
  size_t o_h     = alloc((size_t)N_NODES*D);       // h -> hf later
  size_t o_qkvs  = alloc((size_t)N_NODES*4*D);     // q|k|v|skip -> t1 later
  size_t o_alpha = alloc((size_t)N_EDGES*8);       // alpha -> ex in place
  size_t o_wcat  = alloc((size_t)D*4*D);
  size_t o_bcat  = alloc(4*D);
  size_t o_wmp   = alloc((size_t)320*128/2);       // Wm packed bf16
  size_t o_wep   = alloc((size_t)64*128/2);        // We packed bf16

  float* xnew_out = (float*)d_out;                          // [N, 128]
  float* ea_out   = xnew_out + (size_t)N_NODES*D;           // [E, 64]
  __hip_bfloat16* eproj = (__hip_bfloat16*)ea_out;          // bf16 staging, same bytes

  hipMemsetAsync(d_ws, 0, zero_f*sizeof(float), stream);

  k_deg<<<(N_EDGES+255)/256, 256, 0, stream>>>(src, (int*)(ws+o_deg));
  k_node_prep<<<N_NODES/4, 256, 0, stream>>>(x, (int*)(ws+o_deg), deg_emb, ln_g, ln_b,
                                             ws+o_xin, ws+o_h);
  k_pack<<<(D*4*D + 4*D + 255)/256, 256, 0, stream>>>(Wq,Wk,Wv,Ws, bq,bk,bv,bs,
                                                      ws+o_wcat, ws+o_bcat);
  k_packW<<<160, 256, 0, stream>>>(Wm, (__hip_bfloat16*)(ws+o_wmp), 320);
  k_packW<<<32,  256, 0, stream>>>(We, (__hip_bfloat16*)(ws+o_wep), 64);
  {
    dim3 g((N_NODES+63)/64, 8);
    k_sgemm<0,false,float><<<g,256,0,stream>>>(ws+o_h, ws+o_wcat, ws+o_bcat, nullptr,
                                               ws+o_qkvs, N_NODES, D, 4*D);
  }
  k_eproj_mfma<<<N_EDGES/64, 256, 0, stream>>>(eattr, (const __hip_bfloat16*)(ws+o_wep),
                                               be, eproj);
  k_alpha<<<N_EDGES/4, 256, 0, stream>>>(src, dst, ws+o_qkvs, eproj,
                                         ws+o_alpha, (unsigned*)(ws+o_amax));
  k_amax_fin<<<(N_NODES*8+255)/256, 256, 0, stream>>>((unsigned*)(ws+o_amax));
  k_ex<<<N_EDGES*8/256, 256, 0, stream>>>(dst, ws+o_alpha, ws+o_amax, ws+o_denom);
  k_msg<<<N_EDGES/4, 256, 0, stream>>>(src, dst, ws+o_qkvs, eproj,
                                       ws+o_alpha, ws+o_denom, ws+o_attn);
  k_post_attn<<<N_NODES/4, 256, 0, stream>>>(ws+o_xin, ws+o_qkvs, ln_g, ln_b,
                                             ws+o_attn, ws+o_h);
  {
    dim3 g((N_NODES+63)/64, 8);   // FFN1: t1 = gelu(hf@W1+b1) -> qkvs region
    k_sgemm<1,false,float><<<g,256,0,stream>>>(ws+o_h, W1, b1, nullptr,
                                               ws+o_qkvs, N_NODES, D, 4*D);
  }
  {
    dim3 g((N_NODES+63)/64, 2);   // FFN2: x_new = t1@W2+b2 + x_attn -> d_out
    k_sgemm<0,true,float><<<g,256,0,stream>>>(ws+o_qkvs, W2, b2, ws+o_attn,
                                              xnew_out, N_NODES, 4*D, D);
  }
  k_xn<<<N_NODES/4, 256, 0, stream>>>(xnew_out, eug, eub, ws+o_xin);
  k_edge_mfma2<<<N_EDGES/64, 256, 0, stream>>>(src, dst, ws+o_xin, eattr,
                                               (const __hip_bfloat16*)(ws+o_wmp), bm,
                                               eg, eb, ea_out);
}

// Round 4
// 1255.826 us; speedup vs baseline: 2.8474x; 1.1313x over previous
//
#include <hip/hip_runtime.h>
#include <hip/hip_bf16.h>
#include <math.h>

constexpr int N_NODES = 50000;
constexpr int N_EDGES = 800000;
constexpr int D  = 128;
constexpr int ED = 64;

typedef __attribute__((ext_vector_type(8))) short short8;
typedef __attribute__((ext_vector_type(4))) float f32x4;

static __device__ __forceinline__ float allsum64(float v){
#pragma unroll
  for(int off=32; off>=1; off>>=1) v += __shfl_xor(v, off, 64);
  return v;
}

static __device__ __forceinline__ short bfs(float f){
  __hip_bfloat16 h = __float2bfloat16(f);
  return *reinterpret_cast<short*>(&h);
}
static __device__ __forceinline__ float bf2f(short s){
  __hip_bfloat16 h = *reinterpret_cast<__hip_bfloat16*>(&s);
  return __bfloat162float(h);
}

template<typename T> __device__ __forceinline__ T cvt_out(float v);
template<> __device__ __forceinline__ float cvt_out<float>(float v){ return v; }
template<> __device__ __forceinline__ __hip_bfloat16 cvt_out<__hip_bfloat16>(float v){ return __float2bfloat16(v); }

// ---------------- degree count (src for embedding) + dst histogram (CSR) ----------------
__global__ void k_deg(const int* __restrict__ src, const int* __restrict__ dst,
                      int* __restrict__ deg, int* __restrict__ hist){
  int i = blockIdx.x*256 + threadIdx.x;
  if(i < N_EDGES){
    atomicAdd(&deg[src[i]], 1);
    atomicAdd(&hist[dst[i]], 1);
  }
}

// ---------------- exclusive scan over dst histogram -> rowstart, cursor ----------------
__global__ __launch_bounds__(1024) void k_scan(const int* __restrict__ hist,
                                               int* __restrict__ rows,
                                               int* __restrict__ cursor){
  __shared__ int part[1024];
  const int t = threadIdx.x;
  const int CH = (N_NODES + 1023) / 1024;   // 49
  int base = t*CH;
  int s = 0;
  for(int i=0;i<CH;i++){ int idx=base+i; if(idx<N_NODES) s += hist[idx]; }
  part[t] = s; __syncthreads();
  for(int off=1; off<1024; off<<=1){
    int v = (t>=off) ? part[t-off] : 0;
    __syncthreads();
    part[t] += v;
    __syncthreads();
  }
  int run = part[t] - s;   // exclusive prefix of this chunk
  for(int i=0;i<CH;i++){
    int idx=base+i;
    if(idx<N_NODES){ rows[idx]=run; cursor[idx]=run; run += hist[idx]; }
  }
  if(t==1023) rows[N_NODES] = run;
}

// ---------------- scatter edge ids into dst-sorted perm ----------------
__global__ void k_scatter(const int* __restrict__ dst, int* __restrict__ cursor,
                          int* __restrict__ perm){
  int e = blockIdx.x*256 + threadIdx.x;
  if(e < N_EDGES){
    int p = atomicAdd(&cursor[dst[e]], 1);
    perm[p] = e;
  }
}

// ---------------- x_in = x + deg_emb ; h = LN(x_in) ----------------
__global__ __launch_bounds__(256) void k_node_prep(
    const float* __restrict__ x, const int* __restrict__ deg,
    const float* __restrict__ deg_emb, const float* __restrict__ g,
    const float* __restrict__ b, float* __restrict__ xin, float* __restrict__ h){
  int node = blockIdx.x*4 + (threadIdx.x>>6);
  int lane = threadIdx.x & 63;
  if(node >= N_NODES) return;
  int dg = deg[node]; dg = dg > 511 ? 511 : dg;
  const float* xr = x + (size_t)node*D;
  const float* er = deg_emb + (size_t)dg*D;
  float a0 = xr[lane]    + er[lane];
  float a1 = xr[lane+64] + er[lane+64];
  float* xo = xin + (size_t)node*D;
  xo[lane] = a0; xo[lane+64] = a1;
  float s  = allsum64(a0+a1);
  float s2 = allsum64(a0*a0 + a1*a1);
  float mean = s * (1.f/128.f);
  float var  = s2 * (1.f/128.f) - mean*mean;
  float rs = rsqrtf(var + 1e-5f);
  float* ho = h + (size_t)node*D;
  ho[lane]    = (a0-mean)*rs*g[lane]    + b[lane];
  ho[lane+64] = (a1-mean)*rs*g[lane+64] + b[lane+64];
}

// ---------------- pack Wq|Wk|Wv|Wskip into [128][512] ----------------
__global__ void k_pack(const float* __restrict__ Wq, const float* __restrict__ Wk,
                       const float* __restrict__ Wv, const float* __restrict__ Ws,
                       const float* __restrict__ bq, const float* __restrict__ bk,
                       const float* __restrict__ bv, const float* __restrict__ bs,
                       float* __restrict__ Wcat, float* __restrict__ bcat){
  int idx = blockIdx.x*256 + threadIdx.x;
  if(idx < D*4*D){
    int i = idx >> 9, j = idx & 511;
    int sel = j >> 7, jj = j & 127;
    const float* W = sel==0?Wq: sel==1?Wk: sel==2?Wv:Ws;
    Wcat[idx] = W[i*D + jj];
  } else if(idx < D*4*D + 4*D){
    int j = idx - D*4*D;
    int sel = j>>7, jj = j&127;
    const float* B = sel==0?bq: sel==1?bk: sel==2?bv:bs;
    bcat[j] = B[jj];
  }
}

// ---------------- pack f32 W[K][128] -> bf16 MFMA-B-fragment order ----------------
__global__ void k_packW(const float* __restrict__ W, __hip_bfloat16* __restrict__ out, int K){
  int idx = blockIdx.x*256 + threadIdx.x;
  if(idx >= K*128) return;
  int j  = idx & 7;
  int l  = (idx>>3) & 63;
  int cf = (idx>>9) & 7;
  int kc = idx >> 12;
  int k = kc*32 + ((l>>4)<<3) + j;
  int n = (cf<<4) + (l&15);
  out[idx] = __float2bfloat16(W[k*128 + n]);
}

// ---------------- generic f32 SGEMM: C = act(A@B + bias) (+Src) ----------------
template<int ACT, bool SRCADD, typename OutT>
__global__ __launch_bounds__(256) void k_sgemm(
    const float* __restrict__ A, const float* __restrict__ B,
    const float* __restrict__ bias, const float* __restrict__ Src,
    OutT* __restrict__ C, int M, int K, int Nc){
  __shared__ float As[64*33];
  __shared__ float Bs[32*68];
  const int tid = threadIdx.x;
  const int tx = tid & 15, ty = tid >> 4;
  const int bm0 = blockIdx.x * 64;
  const int bn0 = blockIdx.y * 64;
  const int arow = tid >> 2, acol = (tid & 3)*8;
  const int brow = tid >> 3, bcol = (tid & 7)*8;
  float acc[4][4] = {};
  for(int k0 = 0; k0 < K; k0 += 32){
    int gr = bm0 + arow;
    float* as = &As[arow*33 + acol];
    if(gr < M){
      const float* ap = A + (size_t)gr*K + k0 + acol;
      float4 v0 = *(const float4*)ap;
      float4 v1 = *(const float4*)(ap+4);
      as[0]=v0.x; as[1]=v0.y; as[2]=v0.z; as[3]=v0.w;
      as[4]=v1.x; as[5]=v1.y; as[6]=v1.z; as[7]=v1.w;
    } else {
#pragma unroll
      for(int i=0;i<8;i++) as[i]=0.f;
    }
    {
      const float* bp = B + (size_t)(k0+brow)*Nc + bn0 + bcol;
      float4 v0 = *(const float4*)bp;
      float4 v1 = *(const float4*)(bp+4);
      *(float4*)&Bs[brow*68 + bcol]   = v0;
      *(float4*)&Bs[brow*68 + bcol+4] = v1;
    }
    __syncthreads();
#pragma unroll
    for(int k=0;k<32;k++){
      float a0 = As[(ty*4+0)*33 + k];
      float a1 = As[(ty*4+1)*33 + k];
      float a2 = As[(ty*4+2)*33 + k];
      float a3 = As[(ty*4+3)*33 + k];
      float4 bv = *(float4*)&Bs[k*68 + tx*4];
      acc[0][0] += a0*bv.x; acc[0][1] += a0*bv.y; acc[0][2] += a0*bv.z; acc[0][3] += a0*bv.w;
      acc[1][0] += a1*bv.x; acc[1][1] += a1*bv.y; acc[1][2] += a1*bv.z; acc[1][3] += a1*bv.w;
      acc[2][0] += a2*bv.x; acc[2][1] += a2*bv.y; acc[2][2] += a2*bv.z; acc[2][3] += a2*bv.w;
      acc[3][0] += a3*bv.x; acc[3][1] += a3*bv.y; acc[3][2] += a3*bv.z; acc[3][3] += a3*bv.w;
    }
    __syncthreads();
  }
  const int c0 = bn0 + tx*4;
#pragma unroll
  for(int i=0;i<4;i++){
    int r = bm0 + ty*4 + i;
    if(r >= M) continue;
#pragma unroll
    for(int j=0;j<4;j++){
      float v = acc[i][j] + bias[c0+j];
      if(ACT == 1) v = v * 0.5f * (1.f + erff(v * 0.70710678118f));
      if(SRCADD) v += Src[(size_t)r*Nc + c0 + j];
      C[(size_t)r*Nc + c0 + j] = cvt_out<OutT>(v);
    }
  }
}

// ---------------- e-projection via MFMA: eproj = bf16(edge_attr @ We + be) ----------------
__global__ __launch_bounds__(256) void k_eproj_mfma(
    const float* __restrict__ eattr, const __hip_bfloat16* __restrict__ Wep,
    const float* __restrict__ be, __hip_bfloat16* __restrict__ out){
  const int tid = threadIdx.x, lane = tid & 63, wid = tid >> 6;
  const int l16 = lane & 15, lg = lane >> 4;
  const size_t row = (size_t)blockIdx.x*64 + wid*16;
  f32x4 acc[8] = {};
  const short8* Bg = ((const short8*)Wep) + lane;
  const float* ga = eattr + (row + l16)*64;
#pragma unroll
  for(int kc=0;kc<2;kc++){
    int cb = kc*32 + lg*8;
    float4 f0 = *(const float4*)(ga + cb);
    float4 f1 = *(const float4*)(ga + cb + 4);
    short8 a;
    a[0]=bfs(f0.x); a[1]=bfs(f0.y); a[2]=bfs(f0.z); a[3]=bfs(f0.w);
    a[4]=bfs(f1.x); a[5]=bfs(f1.y); a[6]=bfs(f1.z); a[7]=bfs(f1.w);
#pragma unroll
    for(int cf=0;cf<8;cf++){
      short8 b = Bg[(kc*8+cf)*64];
      acc[cf] = __builtin_amdgcn_mfma_f32_16x16x32_bf16(a, b, acc[cf], 0, 0, 0);
    }
  }
#pragma unroll
  for(int cf=0;cf<8;cf++){
    int col = cf*16 + l16;
    float bb = be[col];
#pragma unroll
    for(int r=0;r<4;r++){
      size_t ro = row + lg*4 + r;
      out[ro*128 + col] = __float2bfloat16(acc[cf][r] + bb);
    }
  }
}

// ---------------- fused attention: one wave per dst node ----------------
// online softmax over CSR segment; epilogue fuses x_attn = xin+out+skip and LN->hf.
__global__ __launch_bounds__(256) void k_attn_fused(
    const int* __restrict__ srcIdx, const int* __restrict__ rows,
    const int* __restrict__ perm,
    const float* __restrict__ qkvs, const __hip_bfloat16* __restrict__ eproj,
    const float* __restrict__ xin, const float* __restrict__ g,
    const float* __restrict__ b,
    float* __restrict__ xattn, float* __restrict__ hf){
  int n = blockIdx.x*4 + (threadIdx.x>>6);
  int lane = threadIdx.x & 63;
  if(n >= N_NODES) return;
  const float* qrow = qkvs + (size_t)n*512;
  float q0 = qrow[lane], q1 = qrow[lane+64];
  float m0=-INFINITY, m1=-INFINITY;
  float den0=0.f, den1=0.f, acc0=0.f, acc1=0.f;
  const int i1 = rows[n+1];
  for(int i=rows[n]; i<i1; i++){
    int eid = perm[i];
    int s = srcIdx[eid];
    const float* kr = qkvs + (size_t)s*512 + 128;
    const __hip_bfloat16* er = eproj + (size_t)eid*128;
    float e0 = bf2f(((const short*)er)[lane]);
    float e1 = bf2f(((const short*)er)[lane+64]);
    float p0 = q0*(kr[lane]    + e0);
    float p1 = q1*(kr[lane+64] + e1);
    p0 += __shfl_xor(p0,1,64); p0 += __shfl_xor(p0,2,64);
    p0 += __shfl_xor(p0,4,64); p0 += __shfl_xor(p0,8,64);
    p1 += __shfl_xor(p1,1,64); p1 += __shfl_xor(p1,2,64);
    p1 += __shfl_xor(p1,4,64); p1 += __shfl_xor(p1,8,64);
    float a0 = p0*0.25f, a1 = p1*0.25f;
    float v0 = kr[lane+128] + e0;     // v part = qkvs + 256
    float v1 = kr[lane+192] + e1;
    float mn0 = fmaxf(m0,a0), mn1 = fmaxf(m1,a1);
    float sc0 = __expf(m0-mn0), sc1 = __expf(m1-mn1);
    float ex0 = __expf(a0-mn0), ex1 = __expf(a1-mn1);
    den0 = den0*sc0 + ex0;       den1 = den1*sc1 + ex1;
    acc0 = acc0*sc0 + ex0*v0;    acc1 = acc1*sc1 + ex1*v1;
    m0 = mn0; m1 = mn1;
  }
  float o0 = acc0/(den0+1e-16f);
  float o1 = acc1/(den1+1e-16f);
  size_t base = (size_t)n*128;
  float a0 = xin[base+lane]    + o0 + qrow[lane+384];
  float a1 = xin[base+lane+64] + o1 + qrow[lane+448];
  xattn[base+lane] = a0; xattn[base+lane+64] = a1;
  float s  = allsum64(a0+a1);
  float s2 = allsum64(a0*a0 + a1*a1);
  float mean = s * (1.f/128.f);
  float var  = s2 * (1.f/128.f) - mean*mean;
  float rs = rsqrtf(var + 1e-5f);
  hf[base+lane]    = (a0-mean)*rs*g[lane]    + b[lane];
  hf[base+lane+64] = (a1-mean)*rs*g[lane+64] + b[lane+64];
}

// ---------------- xn = LN(x_new) with eu_ln (f32 out) ----------------
__global__ __launch_bounds__(256) void k_xn(
    const float* __restrict__ xnew, const float* __restrict__ g,
    const float* __restrict__ b, float* __restrict__ xn){
  int node = blockIdx.x*4 + (threadIdx.x>>6);
  int lane = threadIdx.x & 63;
  if(node >= N_NODES) return;
  size_t base = (size_t)node*D;
  float a0 = xnew[base+lane];
  float a1 = xnew[base+lane+64];
  float s  = allsum64(a0+a1);
  float s2 = allsum64(a0*a0 + a1*a1);
  float mean = s * (1.f/128.f);
  float var  = s2 * (1.f/128.f) - mean*mean;
  float rs = rsqrtf(var + 1e-5f);
  xn[base+lane]    = (a0-mean)*rs*g[lane]    + b[lane];
  xn[base+lane+64] = (a1-mean)*rs*g[lane+64] + b[lane+64];
}

// ---------------- EdgeUpdate via MFMA, LDS-free, split-precision A ----------------
__global__ __launch_bounds__(256) void k_edge_mfma2(
    const int* __restrict__ src, const int* __restrict__ dst,
    const float* __restrict__ xn, const float* __restrict__ ea,
    const __hip_bfloat16* __restrict__ Wmp, const float* __restrict__ bm,
    const float* __restrict__ eg, const float* __restrict__ ebv,
    float* __restrict__ out){
  const int tid = threadIdx.x, lane = tid & 63, wid = tid >> 6;
  const int l16 = lane & 15, lg = lane >> 4;
  const size_t e0 = (size_t)blockIdx.x*64 + wid*16;
  const size_t myrow = e0 + l16;
  const int s = src[myrow], d = dst[myrow];
  f32x4 acc[8] = {};
  const short8* Bg = ((const short8*)Wmp) + lane;
  const int ko = lg*8;

#pragma unroll
  for(int kc=0; kc<10; kc++){
    const float* ap;
    if(kc < 4)      ap = xn + (size_t)s*128 + kc*32 + ko;
    else if(kc < 8) ap = xn + (size_t)d*128 + (kc-4)*32 + ko;
    else            ap = ea + myrow*64 + (kc-8)*32 + ko;
    float4 f0 = *(const float4*)ap;
    float4 f1 = *(const float4*)(ap+4);
    float v[8] = {f0.x,f0.y,f0.z,f0.w,f1.x,f1.y,f1.z,f1.w};
    short8 ah, al;
#pragma unroll
    for(int j=0;j<8;j++){
      short h = bfs(v[j]);
      ah[j] = h;
      al[j] = bfs(v[j] - bf2f(h));
    }
#pragma unroll
    for(int cf=0;cf<8;cf++){
      short8 b = Bg[(kc*8+cf)*64];
      acc[cf] = __builtin_amdgcn_mfma_f32_16x16x32_bf16(ah, b, acc[cf], 0, 0, 0);
      acc[cf] = __builtin_amdgcn_mfma_f32_16x16x32_bf16(al, b, acc[cf], 0, 0, 0);
    }
  }

  float bmd[4], bmg[4], egc[4], ebc[4];
#pragma unroll
  for(int cf=0;cf<4;cf++){
    int col = cf*16 + l16;
    bmd[cf] = bm[col];
    bmg[cf] = bm[64+col];
    egc[cf] = eg[col];
    ebc[cf] = ebv[col];
  }
#pragma unroll
  for(int r=0;r<4;r++){
    size_t erow = e0 + lg*4 + r;
    float u[4];
    float s1 = 0.f, s2 = 0.f;
#pragma unroll
    for(int cf=0;cf<4;cf++){
      float dlt = fmaxf(0.f, acc[cf][r]   + bmd[cf]);
      float gt  = fmaxf(0.f, acc[cf+4][r] + bmg[cf]);
      float uu = ea[erow*64 + cf*16 + l16] + dlt / (1.f + expf(-gt));
      u[cf] = uu; s1 += uu; s2 += uu*uu;
    }
#pragma unroll
    for(int off=1; off<16; off<<=1){
      s1 += __shfl_xor(s1, off, 64);
      s2 += __shfl_xor(s2, off, 64);
    }
    float mean = s1 * (1.f/64.f);
    float var  = s2 * (1.f/64.f) - mean*mean;
    float rs = rsqrtf(var + 1e-5f);
#pragma unroll
    for(int cf=0;cf<4;cf++)
      out[erow*64 + cf*16 + l16] = (u[cf]-mean)*rs*egc[cf] + ebc[cf];
  }
}

extern "C" void kernel_launch(void* const* d_in, const int* in_sizes, int n_in,
                              void* d_out, int out_size, void* d_ws, size_t ws_size,
                              hipStream_t stream){
  const float* x       = (const float*)d_in[0];
  const int*   eidx    = (const int*)d_in[1];
  const float* eattr   = (const float*)d_in[2];
  const float* deg_emb = (const float*)d_in[3];
  const float* ln_g = (const float*)d_in[4];
  const float* ln_b = (const float*)d_in[5];
  const float* Wq = (const float*)d_in[6];  const float* bq = (const float*)d_in[7];
  const float* Wk = (const float*)d_in[8];  const float* bk = (const float*)d_in[9];
  const float* Wv = (const float*)d_in[10]; const float* bv = (const float*)d_in[11];
  const float* We = (const float*)d_in[12]; const float* be = (const float*)d_in[13];
  const float* Ws = (const float*)d_in[14]; const float* bs = (const float*)d_in[15];
  const float* W1 = (const float*)d_in[16]; const float* b1 = (const float*)d_in[17];
  const float* W2 = (const float*)d_in[18]; const float* b2 = (const float*)d_in[19];
  const float* eug = (const float*)d_in[20]; const float* eub = (const float*)d_in[21];
  const float* Wm = (const float*)d_in[22]; const float* bm = (const float*)d_in[23];
  const float* eg = (const float*)d_in[24]; const float* eb = (const float*)d_in[25];
  (void)in_sizes; (void)n_in; (void)out_size; (void)ws_size;

  const int* src = eidx;
  const int* dst = eidx + N_EDGES;

  float* ws = (float*)d_ws;
  size_t o = 0;
  auto alloc = [&](size_t n){ size_t r = o; o += (n + 63) & ~(size_t)63; return r; };
  size_t o_deg   = alloc(N_NODES);                 // int, memset
  size_t o_hist  = alloc(N_NODES);                 // int, memset
  size_t zero_f  = o;                              // memset region end
  size_t o_rows  = alloc(N_NODES+1);               // int
  size_t o_cur   = alloc(N_NODES);                 // int
  size_t o_perm  = alloc(N_EDGES);                 // int
  size_t o_attn  = alloc((size_t)N_NODES*D);       // x_attn (f32)
  size_t o_xin   = alloc((size_t)N_NODES*D);       // x_in -> xn (f32) later
  size_t o_h     = alloc((size_t)N_NODES*D);       // h -> hf later
  size_t o_qkvs  = alloc((size_t)N_NODES*4*D);     // q|k|v|skip -> t1 later
  size_t o_wcat  = alloc((size_t)D*4*D);
  size_t o_bcat  = alloc(4*D);
  size_t o_wmp   = alloc((size_t)320*128/2);       // Wm packed bf16
  size_t o_wep   = alloc((size_t)64*128/2);        // We packed bf16

  float* xnew_out = (float*)d_out;                          // [N, 128]
  float* ea_out   = xnew_out + (size_t)N_NODES*D;           // [E, 64]
  __hip_bfloat16* eproj = (__hip_bfloat16*)ea_out;          // bf16 staging, same bytes

  hipMemsetAsync(d_ws, 0, zero_f*sizeof(float), stream);

  k_deg<<<(N_EDGES+255)/256, 256, 0, stream>>>(src, dst, (int*)(ws+o_deg),
                                               (int*)(ws+o_hist));
  k_scan<<<1, 1024, 0, stream>>>((int*)(ws+o_hist), (int*)(ws+o_rows),
                                 (int*)(ws+o_cur));
  k_scatter<<<(N_EDGES+255)/256, 256, 0, stream>>>(dst, (int*)(ws+o_cur),
                                                   (int*)(ws+o_perm));
  k_node_prep<<<N_NODES/4, 256, 0, stream>>>(x, (int*)(ws+o_deg), deg_emb, ln_g, ln_b,
                                             ws+o_xin, ws+o_h);
  k_pack<<<(D*4*D + 4*D + 255)/256, 256, 0, stream>>>(Wq,Wk,Wv,Ws, bq,bk,bv,bs,
                                                      ws+o_wcat, ws+o_bcat);
  k_packW<<<160, 256, 0, stream>>>(Wm, (__hip_bfloat16*)(ws+o_wmp), 320);
  k_packW<<<32,  256, 0, stream>>>(We, (__hip_bfloat16*)(ws+o_wep), 64);
  {
    dim3 g((N_NODES+63)/64, 8);
    k_sgemm<0,false,float><<<g,256,0,stream>>>(ws+o_h, ws+o_wcat, ws+o_bcat, nullptr,
                                               ws+o_qkvs, N_NODES, D, 4*D);
  }
  k_eproj_mfma<<<N_EDGES/64, 256, 0, stream>>>(eattr, (const __hip_bfloat16*)(ws+o_wep),
                                               be, eproj);
  k_attn_fused<<<(N_NODES+3)/4, 256, 0, stream>>>(src, (int*)(ws+o_rows),
                                                  (int*)(ws+o_perm),
                                                  ws+o_qkvs, eproj, ws+o_xin,
                                                  ln_g, ln_b,
                                                  ws+o_attn, ws+o_h);
  {
    dim3 g((N_NODES+63)/64, 8);   // FFN1: t1 = gelu(hf@W1+b1) -> qkvs region
    k_sgemm<1,false,float><<<g,256,0,stream>>>(ws+o_h, W1, b1, nullptr,
                                               ws+o_qkvs, N_NODES, D, 4*D);
  }
  {
    dim3 g((N_NODES+63)/64, 2);   // FFN2: x_new = t1@W2+b2 + x_attn -> d_out
    k_sgemm<0,true,float><<<g,256,0,stream>>>(ws+o_qkvs, W2, b2, ws+o_attn,
                                              xnew_out, N_NODES, 4*D, D);
  }
  k_xn<<<N_NODES/4, 256, 0, stream>>>(xnew_out, eug, eub, ws+o_xin);
  k_edge_mfma2<<<N_EDGES/64, 256, 0, stream>>>(src, dst, ws+o_xin, eattr,
                                               (const __hip_bfloat16*)(ws+o_wmp), bm,
                                               eg, eb, ea_out);
}

// Round 5
// 1022.747 us; speedup vs baseline: 3.4964x; 1.2279x over previous
//
#include <hip/hip_runtime.h>
#include <hip/hip_bf16.h>
#include <math.h>

constexpr int N_NODES = 50000;
constexpr int N_EDGES = 800000;
constexpr int D  = 128;
constexpr int ED = 64;

typedef __attribute__((ext_vector_type(8))) short short8;
typedef __attribute__((ext_vector_type(4))) float f32x4;

static __device__ __forceinline__ float allsum64(float v){
#pragma unroll
  for(int off=32; off>=1; off>>=1) v += __shfl_xor(v, off, 64);
  return v;
}

static __device__ __forceinline__ short bfs(float f){
  __hip_bfloat16 h = __float2bfloat16(f);
  return *reinterpret_cast<short*>(&h);
}
static __device__ __forceinline__ float bf2f(short s){
  __hip_bfloat16 h = *reinterpret_cast<__hip_bfloat16*>(&s);
  return __bfloat162float(h);
}

template<typename T> __device__ __forceinline__ T cvt_out(float v);
template<> __device__ __forceinline__ float cvt_out<float>(float v){ return v; }
template<> __device__ __forceinline__ __hip_bfloat16 cvt_out<__hip_bfloat16>(float v){ return __float2bfloat16(v); }

// ---------------- degree count (src) + dst histogram (CSR) ----------------
__global__ void k_deg(const int* __restrict__ src, const int* __restrict__ dst,
                      int* __restrict__ deg, int* __restrict__ hist){
  int i = blockIdx.x*256 + threadIdx.x;
  if(i < N_EDGES){
    atomicAdd(&deg[src[i]], 1);
    atomicAdd(&hist[dst[i]], 1);
  }
}

// ---------------- exclusive scan over dst histogram ----------------
__global__ __launch_bounds__(1024) void k_scan(const int* __restrict__ hist,
                                               int* __restrict__ rows,
                                               int* __restrict__ cursor){
  __shared__ int part[1024];
  const int t = threadIdx.x;
  const int CH = (N_NODES + 1023) / 1024;
  int base = t*CH;
  int s = 0;
  for(int i=0;i<CH;i++){ int idx=base+i; if(idx<N_NODES) s += hist[idx]; }
  part[t] = s; __syncthreads();
  for(int off=1; off<1024; off<<=1){
    int v = (t>=off) ? part[t-off] : 0;
    __syncthreads();
    part[t] += v;
    __syncthreads();
  }
  int run = part[t] - s;
  for(int i=0;i<CH;i++){
    int idx=base+i;
    if(idx<N_NODES){ rows[idx]=run; cursor[idx]=run; run += hist[idx]; }
  }
  if(t==1023) rows[N_NODES] = run;
}

// ---------------- scatter edge ids into dst-sorted perm ----------------
__global__ void k_scatter(const int* __restrict__ dst, int* __restrict__ cursor,
                          int* __restrict__ perm){
  int e = blockIdx.x*256 + threadIdx.x;
  if(e < N_EDGES){
    int p = atomicAdd(&cursor[dst[e]], 1);
    perm[p] = e;
  }
}

// ---------------- x_in = x + deg_emb ; h = LN(x_in) ----------------
__global__ __launch_bounds__(256) void k_node_prep(
    const float* __restrict__ x, const int* __restrict__ deg,
    const float* __restrict__ deg_emb, const float* __restrict__ g,
    const float* __restrict__ b, float* __restrict__ xin, float* __restrict__ h){
  int node = blockIdx.x*4 + (threadIdx.x>>6);
  int lane = threadIdx.x & 63;
  if(node >= N_NODES) return;
  int dg = deg[node]; dg = dg > 511 ? 511 : dg;
  const float* xr = x + (size_t)node*D;
  const float* er = deg_emb + (size_t)dg*D;
  float a0 = xr[lane]    + er[lane];
  float a1 = xr[lane+64] + er[lane+64];
  float* xo = xin + (size_t)node*D;
  xo[lane] = a0; xo[lane+64] = a1;
  float s  = allsum64(a0+a1);
  float s2 = allsum64(a0*a0 + a1*a1);
  float mean = s * (1.f/128.f);
  float var  = s2 * (1.f/128.f) - mean*mean;
  float rs = rsqrtf(var + 1e-5f);
  float* ho = h + (size_t)node*D;
  ho[lane]    = (a0-mean)*rs*g[lane]    + b[lane];
  ho[lane+64] = (a1-mean)*rs*g[lane+64] + b[lane+64];
}

// ---------------- pack Wq|Wk|Wv|Wskip into [128][512] f32 + bias ----------------
__global__ void k_pack(const float* __restrict__ Wq, const float* __restrict__ Wk,
                       const float* __restrict__ Wv, const float* __restrict__ Ws,
                       const float* __restrict__ bq, const float* __restrict__ bk,
                       const float* __restrict__ bv, const float* __restrict__ bs,
                       float* __restrict__ Wcat, float* __restrict__ bcat){
  int idx = blockIdx.x*256 + threadIdx.x;
  if(idx < D*4*D){
    int i = idx >> 9, j = idx & 511;
    int sel = j >> 7, jj = j & 127;
    const float* W = sel==0?Wq: sel==1?Wk: sel==2?Wv:Ws;
    Wcat[idx] = W[i*D + jj];
  } else if(idx < D*4*D + 4*D){
    int j = idx - D*4*D;
    int sel = j>>7, jj = j&127;
    const float* B = sel==0?bq: sel==1?bk: sel==2?bv:bs;
    bcat[j] = B[jj];
  }
}

// ---------------- pack f32 W[K][Nfull] -> bf16 MFMA-B fragments (128-col slabs) ----------------
// out[(((nb*KC+kc)*8+cf)*64+l)*8+j] = bf16(W[(kc*32+(l>>4)*8+j)*Nfull + nb*128+cf*16+(l&15)])
__global__ void k_packWN(const float* __restrict__ W, short* __restrict__ out,
                         int K, int Nfull){
  int idx = blockIdx.x*256 + threadIdx.x;
  if(idx >= K*Nfull) return;
  int KC = K >> 5;
  int j  = idx & 7;
  int l  = (idx>>3) & 63;
  int cf = (idx>>9) & 7;
  int rest = idx >> 12;
  int kc = rest % KC;
  int nb = rest / KC;
  int k = kc*32 + ((l>>4)<<3) + j;
  int n = nb*128 + (cf<<4) + (l&15);
  out[idx] = bfs(W[(size_t)k*Nfull + n]);
}

// ---------------- generic MFMA GEMM: C = act(A@B + bias) (+Src) ----------------
// grid (ceil(M/64), Nfull/128). Wave = 16 rows x 128 cols. AT: float or short(bf16).
template<int ACT, bool SRCADD, typename OutT, typename AT>
__global__ __launch_bounds__(256) void k_gemm_mfma(
    const AT* __restrict__ A, const short* __restrict__ Wp,
    const float* __restrict__ bias, const float* __restrict__ Src,
    OutT* __restrict__ C, int M, int K, int Nfull){
  const int tid = threadIdx.x, lane = tid & 63, wid = tid >> 6;
  const int l16 = lane & 15, lg = lane >> 4;
  const int KC = K >> 5;
  const size_t rowb = (size_t)blockIdx.x*64 + wid*16;
  const int nb = blockIdx.y;
  size_t arow = rowb + l16; if(arow >= (size_t)M) arow = M-1;
  f32x4 acc[8] = {};
  const short8* Bg = ((const short8*)Wp) + (size_t)nb*KC*512 + lane;
  for(int kc=0; kc<KC; kc++){
    short8 a;
    if constexpr (sizeof(AT)==4){
      const float* ap = (const float*)A + arow*K + kc*32 + lg*8;
      float4 f0 = *(const float4*)ap;
      float4 f1 = *(const float4*)(ap+4);
      a[0]=bfs(f0.x); a[1]=bfs(f0.y); a[2]=bfs(f0.z); a[3]=bfs(f0.w);
      a[4]=bfs(f1.x); a[5]=bfs(f1.y); a[6]=bfs(f1.z); a[7]=bfs(f1.w);
    } else {
      a = *(const short8*)((const short*)A + arow*K + kc*32 + lg*8);
    }
#pragma unroll
    for(int cf=0;cf<8;cf++){
      short8 b = Bg[(kc*8+cf)*64];
      acc[cf] = __builtin_amdgcn_mfma_f32_16x16x32_bf16(a, b, acc[cf], 0, 0, 0);
    }
  }
#pragma unroll
  for(int cf=0;cf<8;cf++){
    int col = nb*128 + cf*16 + l16;
    float bb = bias[col];
#pragma unroll
    for(int r=0;r<4;r++){
      size_t ro = rowb + lg*4 + r;
      if(ro < (size_t)M){
        float v = acc[cf][r] + bb;
        if(ACT == 1) v = v * 0.5f * (1.f + erff(v * 0.70710678118f));
        if(SRCADD) v += Src[ro*Nfull + col];
        C[ro*Nfull + col] = cvt_out<OutT>(v);
      }
    }
  }
}

// ---------------- e-projection via MFMA: eproj = bf16(edge_attr @ We + be) ----------------
__global__ __launch_bounds__(256) void k_eproj_mfma(
    const float* __restrict__ eattr, const short* __restrict__ Wep,
    const float* __restrict__ be, __hip_bfloat16* __restrict__ out){
  const int tid = threadIdx.x, lane = tid & 63, wid = tid >> 6;
  const int l16 = lane & 15, lg = lane >> 4;
  const size_t row = (size_t)blockIdx.x*64 + wid*16;
  f32x4 acc[8] = {};
  const short8* Bg = ((const short8*)Wep) + lane;
  const float* ga = eattr + (row + l16)*64;
#pragma unroll
  for(int kc=0;kc<2;kc++){
    int cb = kc*32 + lg*8;
    float4 f0 = *(const float4*)(ga + cb);
    float4 f1 = *(const float4*)(ga + cb + 4);
    short8 a;
    a[0]=bfs(f0.x); a[1]=bfs(f0.y); a[2]=bfs(f0.z); a[3]=bfs(f0.w);
    a[4]=bfs(f1.x); a[5]=bfs(f1.y); a[6]=bfs(f1.z); a[7]=bfs(f1.w);
#pragma unroll
    for(int cf=0;cf<8;cf++){
      short8 b = Bg[(kc*8+cf)*64];
      acc[cf] = __builtin_amdgcn_mfma_f32_16x16x32_bf16(a, b, acc[cf], 0, 0, 0);
    }
  }
#pragma unroll
  for(int cf=0;cf<8;cf++){
    int col = cf*16 + l16;
    float bb = be[col];
#pragma unroll
    for(int r=0;r<4;r++){
      size_t ro = row + lg*4 + r;
      out[ro*128 + col] = __float2bfloat16(acc[cf][r] + bb);
    }
  }
}

// ---------------- fused attention: one wave per dst node (bf16 qkvs) ----------------
__global__ __launch_bounds__(256) void k_attn_fused(
    const int* __restrict__ srcIdx, const int* __restrict__ rows,
    const int* __restrict__ perm,
    const short* __restrict__ qk, const __hip_bfloat16* __restrict__ eproj,
    const float* __restrict__ xin, const float* __restrict__ g,
    const float* __restrict__ b,
    float* __restrict__ xattn, float* __restrict__ hf){
  int n = blockIdx.x*4 + (threadIdx.x>>6);
  int lane = threadIdx.x & 63;
  if(n >= N_NODES) return;
  const short* qrow = qk + (size_t)n*512;
  float q0 = bf2f(qrow[lane]), q1 = bf2f(qrow[lane+64]);
  float m0=-INFINITY, m1=-INFINITY;
  float den0=0.f, den1=0.f, acc0=0.f, acc1=0.f;
  const int i1 = rows[n+1];
  for(int i=rows[n]; i<i1; i++){
    int eid = perm[i];
    int s = srcIdx[eid];
    const short* kr = qk + (size_t)s*512 + 128;
    const short* er = (const short*)eproj + (size_t)eid*128;
    float e0 = bf2f(er[lane]);
    float e1 = bf2f(er[lane+64]);
    float p0 = q0*(bf2f(kr[lane])    + e0);
    float p1 = q1*(bf2f(kr[lane+64]) + e1);
    p0 += __shfl_xor(p0,1,64); p0 += __shfl_xor(p0,2,64);
    p0 += __shfl_xor(p0,4,64); p0 += __shfl_xor(p0,8,64);
    p1 += __shfl_xor(p1,1,64); p1 += __shfl_xor(p1,2,64);
    p1 += __shfl_xor(p1,4,64); p1 += __shfl_xor(p1,8,64);
    float a0 = p0*0.25f, a1 = p1*0.25f;
    float v0 = bf2f(kr[lane+128]) + e0;
    float v1 = bf2f(kr[lane+192]) + e1;
    float mn0 = fmaxf(m0,a0), mn1 = fmaxf(m1,a1);
    float sc0 = __expf(m0-mn0), sc1 = __expf(m1-mn1);
    float ex0 = __expf(a0-mn0), ex1 = __expf(a1-mn1);
    den0 = den0*sc0 + ex0;       den1 = den1*sc1 + ex1;
    acc0 = acc0*sc0 + ex0*v0;    acc1 = acc1*sc1 + ex1*v1;
    m0 = mn0; m1 = mn1;
  }
  float o0 = acc0/(den0+1e-16f);
  float o1 = acc1/(den1+1e-16f);
  size_t base = (size_t)n*128;
  float a0 = xin[base+lane]    + o0 + bf2f(qrow[lane+384]);
  float a1 = xin[base+lane+64] + o1 + bf2f(qrow[lane+448]);
  xattn[base+lane] = a0; xattn[base+lane+64] = a1;
  float s  = allsum64(a0+a1);
  float s2 = allsum64(a0*a0 + a1*a1);
  float mean = s * (1.f/128.f);
  float var  = s2 * (1.f/128.f) - mean*mean;
  float rs = rsqrtf(var + 1e-5f);
  hf[base+lane]    = (a0-mean)*rs*g[lane]    + b[lane];
  hf[base+lane+64] = (a1-mean)*rs*g[lane+64] + b[lane+64];
}

// ---------------- xn = LN(x_new) with eu_ln -> bf16 ----------------
__global__ __launch_bounds__(256) void k_xn(
    const float* __restrict__ xnew, const float* __restrict__ g,
    const float* __restrict__ b, short* __restrict__ xn){
  int node = blockIdx.x*4 + (threadIdx.x>>6);
  int lane = threadIdx.x & 63;
  if(node >= N_NODES) return;
  size_t base = (size_t)node*D;
  float a0 = xnew[base+lane];
  float a1 = xnew[base+lane+64];
  float s  = allsum64(a0+a1);
  float s2 = allsum64(a0*a0 + a1*a1);
  float mean = s * (1.f/128.f);
  float var  = s2 * (1.f/128.f) - mean*mean;
  float rs = rsqrtf(var + 1e-5f);
  xn[base+lane]    = bfs((a0-mean)*rs*g[lane]    + b[lane]);
  xn[base+lane+64] = bfs((a1-mean)*rs*g[lane+64] + b[lane+64]);
}

// ---------------- EdgeUpdate via MFMA, LDS-free, bf16 single ----------------
// Wave = 16 edges x 128 cols; kc 0-3 xn[src](bf16), 4-7 xn[dst](bf16), 8-9 ea(f32->cvt).
__global__ __launch_bounds__(256) void k_edge_mfma3(
    const int* __restrict__ src, const int* __restrict__ dst,
    const short* __restrict__ xnb, const float* __restrict__ ea,
    const short* __restrict__ Wmp, const float* __restrict__ bm,
    const float* __restrict__ eg, const float* __restrict__ ebv,
    float* __restrict__ out){
  const int tid = threadIdx.x, lane = tid & 63, wid = tid >> 6;
  const int l16 = lane & 15, lg = lane >> 4;
  const size_t e0 = (size_t)blockIdx.x*64 + wid*16;
  const size_t myrow = e0 + l16;
  const int s = src[myrow], d = dst[myrow];
  f32x4 acc[8] = {};
  const short8* Bg = ((const short8*)Wmp) + lane;
  const int ko = lg*8;

#pragma unroll
  for(int kc=0; kc<10; kc++){
    short8 a;
    if(kc < 8){
      const short* ap = (kc < 4) ? (xnb + (size_t)s*128 + kc*32 + ko)
                                 : (xnb + (size_t)d*128 + (kc-4)*32 + ko);
      a = *(const short8*)ap;
    } else {
      const float* ap = ea + myrow*64 + (kc-8)*32 + ko;
      float4 f0 = *(const float4*)ap;
      float4 f1 = *(const float4*)(ap+4);
      a[0]=bfs(f0.x); a[1]=bfs(f0.y); a[2]=bfs(f0.z); a[3]=bfs(f0.w);
      a[4]=bfs(f1.x); a[5]=bfs(f1.y); a[6]=bfs(f1.z); a[7]=bfs(f1.w);
    }
#pragma unroll
    for(int cf=0;cf<8;cf++){
      short8 b = Bg[(kc*8+cf)*64];
      acc[cf] = __builtin_amdgcn_mfma_f32_16x16x32_bf16(a, b, acc[cf], 0, 0, 0);
    }
  }

  float bmd[4], bmg[4], egc[4], ebc[4];
#pragma unroll
  for(int cf=0;cf<4;cf++){
    int col = cf*16 + l16;
    bmd[cf] = bm[col];
    bmg[cf] = bm[64+col];
    egc[cf] = eg[col];
    ebc[cf] = ebv[col];
  }
#pragma unroll
  for(int r=0;r<4;r++){
    size_t erow = e0 + lg*4 + r;
    float u[4];
    float s1 = 0.f, s2 = 0.f;
#pragma unroll
    for(int cf=0;cf<4;cf++){
      float dlt = fmaxf(0.f, acc[cf][r]   + bmd[cf]);
      float gt  = fmaxf(0.f, acc[cf+4][r] + bmg[cf]);
      float uu = ea[erow*64 + cf*16 + l16] + dlt / (1.f + expf(-gt));
      u[cf] = uu; s1 += uu; s2 += uu*uu;
    }
#pragma unroll
    for(int off=1; off<16; off<<=1){
      s1 += __shfl_xor(s1, off, 64);
      s2 += __shfl_xor(s2, off, 64);
    }
    float mean = s1 * (1.f/64.f);
    float var  = s2 * (1.f/64.f) - mean*mean;
    float rs = rsqrtf(var + 1e-5f);
#pragma unroll
    for(int cf=0;cf<4;cf++)
      out[erow*64 + cf*16 + l16] = (u[cf]-mean)*rs*egc[cf] + ebc[cf];
  }
}

extern "C" void kernel_launch(void* const* d_in, const int* in_sizes, int n_in,
                              void* d_out, int out_size, void* d_ws, size_t ws_size,
                              hipStream_t stream){
  const float* x       = (const float*)d_in[0];
  const int*   eidx    = (const int*)d_in[1];
  const float* eattr   = (const float*)d_in[2];
  const float* deg_emb = (const float*)d_in[3];
  const float* ln_g = (const float*)d_in[4];
  const float* ln_b = (const float*)d_in[5];
  const float* Wq = (const float*)d_in[6];  const float* bq = (const float*)d_in[7];
  const float* Wk = (const float*)d_in[8];  const float* bk = (const float*)d_in[9];
  const float* Wv = (const float*)d_in[10]; const float* bv = (const float*)d_in[11];
  const float* We = (const float*)d_in[12]; const float* be = (const float*)d_in[13];
  const float* Ws = (const float*)d_in[14]; const float* bs = (const float*)d_in[15];
  const float* W1 = (const float*)d_in[16]; const float* b1 = (const float*)d_in[17];
  const float* W2 = (const float*)d_in[18]; const float* b2 = (const float*)d_in[19];
  const float* eug = (const float*)d_in[20]; const float* eub = (const float*)d_in[21];
  const float* Wm = (const float*)d_in[22]; const float* bm = (const float*)d_in[23];
  const float* eg = (const float*)d_in[24]; const float* eb = (const float*)d_in[25];
  (void)in_sizes; (void)n_in; (void)out_size; (void)ws_size;

  const int* src = eidx;
  const int* dst = eidx + N_EDGES;

  float* ws = (float*)d_ws;
  size_t o = 0;
  auto alloc = [&](size_t n){ size_t r = o; o += (n + 63) & ~(size_t)63; return r; };
  size_t o_deg   = alloc(N_NODES);                 // int, memset
  size_t o_hist  = alloc(N_NODES);                 // int, memset
  size_t zero_f  = o;
  size_t o_rows  = alloc(N_NODES+1);               // int
  size_t o_cur   = alloc(N_NODES);                 // int
  size_t o_perm  = alloc(N_EDGES);                 // int
  size_t o_attn  = alloc((size_t)N_NODES*D);       // x_attn f32
  size_t o_xin   = alloc((size_t)N_NODES*D);       // x_in f32; xn(bf16) reuses later
  size_t o_h     = alloc((size_t)N_NODES*D);       // h -> hf
  size_t o_qkv16 = alloc((size_t)N_NODES*256);     // qkvs bf16 [N,512]; t1 bf16 reuses
  size_t o_wcat  = alloc((size_t)D*4*D);           // f32 Wcat
  size_t o_bcat  = alloc(4*D);
  size_t o_wqp   = alloc((size_t)128*512/2);       // packed bf16
  size_t o_w1p   = alloc((size_t)128*512/2);
  size_t o_w2p   = alloc((size_t)512*128/2);
  size_t o_wmp   = alloc((size_t)320*128/2);
  size_t o_wep   = alloc((size_t)64*128/2);

  float* xnew_out = (float*)d_out;                          // [N,128]
  float* ea_out   = xnew_out + (size_t)N_NODES*D;           // [E,64]
  __hip_bfloat16* eproj = (__hip_bfloat16*)ea_out;          // bf16 staging

  hipMemsetAsync(d_ws, 0, zero_f*sizeof(float), stream);

  k_deg<<<(N_EDGES+255)/256, 256, 0, stream>>>(src, dst, (int*)(ws+o_deg),
                                               (int*)(ws+o_hist));
  k_scan<<<1, 1024, 0, stream>>>((int*)(ws+o_hist), (int*)(ws+o_rows),
                                 (int*)(ws+o_cur));
  k_scatter<<<(N_EDGES+255)/256, 256, 0, stream>>>(dst, (int*)(ws+o_cur),
                                                   (int*)(ws+o_perm));
  k_node_prep<<<N_NODES/4, 256, 0, stream>>>(x, (int*)(ws+o_deg), deg_emb, ln_g, ln_b,
                                             ws+o_xin, ws+o_h);
  k_pack<<<(D*4*D + 4*D + 255)/256, 256, 0, stream>>>(Wq,Wk,Wv,Ws, bq,bk,bv,bs,
                                                      ws+o_wcat, ws+o_bcat);
  k_packWN<<<256, 256, 0, stream>>>(ws+o_wcat, (short*)(ws+o_wqp), 128, 512);
  k_packWN<<<256, 256, 0, stream>>>(W1, (short*)(ws+o_w1p), 128, 512);
  k_packWN<<<256, 256, 0, stream>>>(W2, (short*)(ws+o_w2p), 512, 128);
  k_packWN<<<160, 256, 0, stream>>>(Wm, (short*)(ws+o_wmp), 320, 128);
  k_packWN<<<32,  256, 0, stream>>>(We, (short*)(ws+o_wep), 64, 128);
  {
    dim3 g((N_NODES+63)/64, 4);    // qkvs = bf16(h @ Wcat + bcat)
    k_gemm_mfma<0,false,__hip_bfloat16,float><<<g,256,0,stream>>>(
        ws+o_h, (const short*)(ws+o_wqp), ws+o_bcat, nullptr,
        (__hip_bfloat16*)(ws+o_qkv16), N_NODES, 128, 512);
  }
  k_eproj_mfma<<<N_EDGES/64, 256, 0, stream>>>(eattr, (const short*)(ws+o_wep),
                                               be, eproj);
  k_attn_fused<<<(N_NODES+3)/4, 256, 0, stream>>>(src, (int*)(ws+o_rows),
                                                  (int*)(ws+o_perm),
                                                  (const short*)(ws+o_qkv16), eproj,
                                                  ws+o_xin, ln_g, ln_b,
                                                  ws+o_attn, ws+o_h);
  {
    dim3 g((N_NODES+63)/64, 4);    // t1 = bf16(gelu(hf @ W1 + b1)) -> qkv16 region
    k_gemm_mfma<1,false,__hip_bfloat16,float><<<g,256,0,stream>>>(
        ws+o_h, (const short*)(ws+o_w1p), b1, nullptr,
        (__hip_bfloat16*)(ws+o_qkv16), N_NODES, 128, 512);
  }
  {
    dim3 g((N_NODES+63)/64, 1);    // x_new = t1 @ W2 + b2 + x_attn -> d_out
    k_gemm_mfma<0,true,float,short><<<g,256,0,stream>>>(
        (const short*)(ws+o_qkv16), (const short*)(ws+o_w2p), b2, ws+o_attn,
        xnew_out, N_NODES, 512, 128);
  }
  k_xn<<<N_NODES/4, 256, 0, stream>>>(xnew_out, eug, eub, (short*)(ws+o_xin));
  k_edge_mfma3<<<N_EDGES/64, 256, 0, stream>>>(src, dst, (const short*)(ws+o_xin),
                                               eattr, (const short*)(ws+o_wmp), bm,
                                               eg, eb, ea_out);
}

// Round 6
// 917.266 us; speedup vs baseline: 3.8984x; 1.1150x over previous
//
#include <hip/hip_runtime.h>
#include <hip/hip_bf16.h>
#include <math.h>

constexpr int N_NODES = 50000;
constexpr int N_EDGES = 800000;
constexpr int D  = 128;
constexpr int ED = 64;

typedef __attribute__((ext_vector_type(8))) short short8;
typedef __attribute__((ext_vector_type(4))) float f32x4;

static __device__ __forceinline__ float allsum64(float v){
#pragma unroll
  for(int off=32; off>=1; off>>=1) v += __shfl_xor(v, off, 64);
  return v;
}

static __device__ __forceinline__ short bfs(float f){
  __hip_bfloat16 h = __float2bfloat16(f);
  return *reinterpret_cast<short*>(&h);
}
static __device__ __forceinline__ float bf2f(short s){
  __hip_bfloat16 h = *reinterpret_cast<__hip_bfloat16*>(&s);
  return __bfloat162float(h);
}

template<typename T> __device__ __forceinline__ T cvt_out(float v);
template<> __device__ __forceinline__ float cvt_out<float>(float v){ return v; }
template<> __device__ __forceinline__ __hip_bfloat16 cvt_out<__hip_bfloat16>(float v){ return __float2bfloat16(v); }

// ---------------- degree count (src) + dst histogram (CSR) ----------------
__global__ void k_deg(const int* __restrict__ src, const int* __restrict__ dst,
                      int* __restrict__ deg, int* __restrict__ hist){
  int i = blockIdx.x*256 + threadIdx.x;
  if(i < N_EDGES){
    atomicAdd(&deg[src[i]], 1);
    atomicAdd(&hist[dst[i]], 1);
  }
}

// ---------------- exclusive scan over dst histogram ----------------
__global__ __launch_bounds__(1024) void k_scan(const int* __restrict__ hist,
                                               int* __restrict__ rows,
                                               int* __restrict__ cursor){
  __shared__ int part[1024];
  const int t = threadIdx.x;
  const int CH = (N_NODES + 1023) / 1024;
  int base = t*CH;
  int s = 0;
  for(int i=0;i<CH;i++){ int idx=base+i; if(idx<N_NODES) s += hist[idx]; }
  part[t] = s; __syncthreads();
  for(int off=1; off<1024; off<<=1){
    int v = (t>=off) ? part[t-off] : 0;
    __syncthreads();
    part[t] += v;
    __syncthreads();
  }
  int run = part[t] - s;
  for(int i=0;i<CH;i++){
    int idx=base+i;
    if(idx<N_NODES){ rows[idx]=run; cursor[idx]=run; run += hist[idx]; }
  }
  if(t==1023) rows[N_NODES] = run;
}

// ---------------- scatter edge ids + src into dst-sorted order ----------------
__global__ void k_scatter(const int* __restrict__ src, const int* __restrict__ dst,
                          int* __restrict__ cursor,
                          int* __restrict__ perm, int* __restrict__ ssrc){
  int e = blockIdx.x*256 + threadIdx.x;
  if(e < N_EDGES){
    int p = atomicAdd(&cursor[dst[e]], 1);
    perm[p] = e;
    ssrc[p] = src[e];
  }
}

// ---------------- x_in = x + deg_emb ; h = LN(x_in) ----------------
__global__ __launch_bounds__(256) void k_node_prep(
    const float* __restrict__ x, const int* __restrict__ deg,
    const float* __restrict__ deg_emb, const float* __restrict__ g,
    const float* __restrict__ b, float* __restrict__ xin, float* __restrict__ h){
  int node = blockIdx.x*4 + (threadIdx.x>>6);
  int lane = threadIdx.x & 63;
  if(node >= N_NODES) return;
  int dg = deg[node]; dg = dg > 511 ? 511 : dg;
  const float* xr = x + (size_t)node*D;
  const float* er = deg_emb + (size_t)dg*D;
  float a0 = xr[lane]    + er[lane];
  float a1 = xr[lane+64] + er[lane+64];
  float* xo = xin + (size_t)node*D;
  xo[lane] = a0; xo[lane+64] = a1;
  float s  = allsum64(a0+a1);
  float s2 = allsum64(a0*a0 + a1*a1);
  float mean = s * (1.f/128.f);
  float var  = s2 * (1.f/128.f) - mean*mean;
  float rs = rsqrtf(var + 1e-5f);
  float* ho = h + (size_t)node*D;
  ho[lane]    = (a0-mean)*rs*g[lane]    + b[lane];
  ho[lane+64] = (a1-mean)*rs*g[lane+64] + b[lane+64];
}

// ---------------- pack Wq|Wk|Wv|Wskip into [128][512] f32 + bias ----------------
__global__ void k_pack(const float* __restrict__ Wq, const float* __restrict__ Wk,
                       const float* __restrict__ Wv, const float* __restrict__ Ws,
                       const float* __restrict__ bq, const float* __restrict__ bk,
                       const float* __restrict__ bv, const float* __restrict__ bs,
                       float* __restrict__ Wcat, float* __restrict__ bcat){
  int idx = blockIdx.x*256 + threadIdx.x;
  if(idx < D*4*D){
    int i = idx >> 9, j = idx & 511;
    int sel = j >> 7, jj = j & 127;
    const float* W = sel==0?Wq: sel==1?Wk: sel==2?Wv:Ws;
    Wcat[idx] = W[i*D + jj];
  } else if(idx < D*4*D + 4*D){
    int j = idx - D*4*D;
    int sel = j>>7, jj = j&127;
    const float* B = sel==0?bq: sel==1?bk: sel==2?bv:bs;
    bcat[j] = B[jj];
  }
}

// ---------------- pack f32 W[K][Nfull] -> bf16 MFMA-B fragments (128-col slabs) ----------------
__global__ void k_packWN(const float* __restrict__ W, short* __restrict__ out,
                         int K, int Nfull){
  int idx = blockIdx.x*256 + threadIdx.x;
  if(idx >= K*Nfull) return;
  int KC = K >> 5;
  int j  = idx & 7;
  int l  = (idx>>3) & 63;
  int cf = (idx>>9) & 7;
  int rest = idx >> 12;
  int kc = rest % KC;
  int nb = rest / KC;
  int k = kc*32 + ((l>>4)<<3) + j;
  int n = nb*128 + (cf<<4) + (l&15);
  out[idx] = bfs(W[(size_t)k*Nfull + n]);
}

// ---------------- generic MFMA GEMM: C = act(A@B + bias) (+Src) ----------------
template<int ACT, bool SRCADD, typename OutT, typename AT>
__global__ __launch_bounds__(256) void k_gemm_mfma(
    const AT* __restrict__ A, const short* __restrict__ Wp,
    const float* __restrict__ bias, const float* __restrict__ Src,
    OutT* __restrict__ C, int M, int K, int Nfull){
  const int tid = threadIdx.x, lane = tid & 63, wid = tid >> 6;
  const int l16 = lane & 15, lg = lane >> 4;
  const int KC = K >> 5;
  const size_t rowb = (size_t)blockIdx.x*64 + wid*16;
  const int nb = blockIdx.y;
  size_t arow = rowb + l16; if(arow >= (size_t)M) arow = M-1;
  f32x4 acc[8] = {};
  const short8* Bg = ((const short8*)Wp) + (size_t)nb*KC*512 + lane;
  for(int kc=0; kc<KC; kc++){
    short8 a;
    if constexpr (sizeof(AT)==4){
      const float* ap = (const float*)A + arow*K + kc*32 + lg*8;
      float4 f0 = *(const float4*)ap;
      float4 f1 = *(const float4*)(ap+4);
      a[0]=bfs(f0.x); a[1]=bfs(f0.y); a[2]=bfs(f0.z); a[3]=bfs(f0.w);
      a[4]=bfs(f1.x); a[5]=bfs(f1.y); a[6]=bfs(f1.z); a[7]=bfs(f1.w);
    } else {
      a = *(const short8*)((const short*)A + arow*K + kc*32 + lg*8);
    }
#pragma unroll
    for(int cf=0;cf<8;cf++){
      short8 b = Bg[(kc*8+cf)*64];
      acc[cf] = __builtin_amdgcn_mfma_f32_16x16x32_bf16(a, b, acc[cf], 0, 0, 0);
    }
  }
#pragma unroll
  for(int cf=0;cf<8;cf++){
    int col = nb*128 + cf*16 + l16;
    float bb = bias[col];
#pragma unroll
    for(int r=0;r<4;r++){
      size_t ro = rowb + lg*4 + r;
      if(ro < (size_t)M){
        float v = acc[cf][r] + bb;
        if(ACT == 1) v = v * 0.5f * (1.f + erff(v * 0.70710678118f));
        if(SRCADD) v += Src[ro*Nfull + col];
        C[ro*Nfull + col] = cvt_out<OutT>(v);
      }
    }
  }
}

// ---------------- e-projection in dst-sorted order: es[i] = bf16(eattr[perm[i]] @ We + be) ----------------
__global__ __launch_bounds__(256) void k_eproj_sorted(
    const float* __restrict__ eattr, const int* __restrict__ perm,
    const short* __restrict__ Wep, const float* __restrict__ be,
    __hip_bfloat16* __restrict__ out){
  const int tid = threadIdx.x, lane = tid & 63, wid = tid >> 6;
  const int l16 = lane & 15, lg = lane >> 4;
  const size_t row = (size_t)blockIdx.x*64 + wid*16;
  const int pe = perm[row + l16];
  f32x4 acc[8] = {};
  const short8* Bg = ((const short8*)Wep) + lane;
  const float* ga = eattr + (size_t)pe*64;
#pragma unroll
  for(int kc=0;kc<2;kc++){
    int cb = kc*32 + lg*8;
    float4 f0 = *(const float4*)(ga + cb);
    float4 f1 = *(const float4*)(ga + cb + 4);
    short8 a;
    a[0]=bfs(f0.x); a[1]=bfs(f0.y); a[2]=bfs(f0.z); a[3]=bfs(f0.w);
    a[4]=bfs(f1.x); a[5]=bfs(f1.y); a[6]=bfs(f1.z); a[7]=bfs(f1.w);
#pragma unroll
    for(int cf=0;cf<8;cf++){
      short8 b = Bg[(kc*8+cf)*64];
      acc[cf] = __builtin_amdgcn_mfma_f32_16x16x32_bf16(a, b, acc[cf], 0, 0, 0);
    }
  }
#pragma unroll
  for(int cf=0;cf<8;cf++){
    int col = cf*16 + l16;
    float bb = be[col];
#pragma unroll
    for(int r=0;r<4;r++){
      size_t ro = row + lg*4 + r;
      out[ro*128 + col] = __float2bfloat16(acc[cf][r] + bb);
    }
  }
}

// ---------------- fused attention v2: sequential es rows + shallow k/v gather ----------------
__global__ __launch_bounds__(256) void k_attn_fused2(
    const int* __restrict__ ssrc, const int* __restrict__ rows,
    const short* __restrict__ qk, const short* __restrict__ es,
    const float* __restrict__ xin, const float* __restrict__ g,
    const float* __restrict__ b,
    float* __restrict__ xattn, float* __restrict__ hf){
  int n = blockIdx.x*4 + (threadIdx.x>>6);
  int lane = threadIdx.x & 63;
  if(n >= N_NODES) return;
  const short* qrow = qk + (size_t)n*512;
  float q0 = bf2f(qrow[lane]), q1 = bf2f(qrow[lane+64]);
  float m0=-INFINITY, m1=-INFINITY;
  float den0=0.f, den1=0.f, acc0=0.f, acc1=0.f;
  int i = rows[n];
  const int i1 = rows[n+1];

  auto body = [&](float eA0, float eA1, float kv0, float kv1, float kv2, float kv3){
    float p0 = q0*(kv0 + eA0);
    float p1 = q1*(kv1 + eA1);
    p0 += __shfl_xor(p0,1,64); p0 += __shfl_xor(p0,2,64);
    p0 += __shfl_xor(p0,4,64); p0 += __shfl_xor(p0,8,64);
    p1 += __shfl_xor(p1,1,64); p1 += __shfl_xor(p1,2,64);
    p1 += __shfl_xor(p1,4,64); p1 += __shfl_xor(p1,8,64);
    float a0 = p0*0.25f, a1 = p1*0.25f;
    float v0 = kv2 + eA0, v1 = kv3 + eA1;
    float mn0 = fmaxf(m0,a0), mn1 = fmaxf(m1,a1);
    float sc0 = __expf(m0-mn0), sc1 = __expf(m1-mn1);
    float ex0 = __expf(a0-mn0), ex1 = __expf(a1-mn1);
    den0 = den0*sc0 + ex0;       den1 = den1*sc1 + ex1;
    acc0 = acc0*sc0 + ex0*v0;    acc1 = acc1*sc1 + ex1*v1;
    m0 = mn0; m1 = mn1;
  };

  for(; i+2 <= i1; i += 2){
    int sA = ssrc[i], sB = ssrc[i+1];
    const short* eA = es + (size_t)i*128;
    const short* kA = qk + (size_t)sA*512 + 128;
    const short* kB = qk + (size_t)sB*512 + 128;
    float eA0=bf2f(eA[lane]),      eA1=bf2f(eA[lane+64]);
    float eB0=bf2f(eA[lane+128]),  eB1=bf2f(eA[lane+192]);
    float kA0=bf2f(kA[lane]),      kA1=bf2f(kA[lane+64]);
    float vA0=bf2f(kA[lane+128]),  vA1=bf2f(kA[lane+192]);
    float kB0=bf2f(kB[lane]),      kB1=bf2f(kB[lane+64]);
    float vB0=bf2f(kB[lane+128]),  vB1=bf2f(kB[lane+192]);
    // two independent dot/reduce chains interleaved by the compiler
    float pA0 = q0*(kA0+eA0), pA1 = q1*(kA1+eA1);
    float pB0 = q0*(kB0+eB0), pB1 = q1*(kB1+eB1);
#pragma unroll
    for(int off=1; off<16; off<<=1){
      pA0 += __shfl_xor(pA0,off,64); pA1 += __shfl_xor(pA1,off,64);
      pB0 += __shfl_xor(pB0,off,64); pB1 += __shfl_xor(pB1,off,64);
    }
    {
      float a0 = pA0*0.25f, a1 = pA1*0.25f;
      float v0 = vA0+eA0, v1 = vA1+eA1;
      float mn0 = fmaxf(m0,a0), mn1 = fmaxf(m1,a1);
      float sc0 = __expf(m0-mn0), sc1 = __expf(m1-mn1);
      float ex0 = __expf(a0-mn0), ex1 = __expf(a1-mn1);
      den0 = den0*sc0 + ex0;       den1 = den1*sc1 + ex1;
      acc0 = acc0*sc0 + ex0*v0;    acc1 = acc1*sc1 + ex1*v1;
      m0 = mn0; m1 = mn1;
    }
    {
      float a0 = pB0*0.25f, a1 = pB1*0.25f;
      float v0 = vB0+eB0, v1 = vB1+eB1;
      float mn0 = fmaxf(m0,a0), mn1 = fmaxf(m1,a1);
      float sc0 = __expf(m0-mn0), sc1 = __expf(m1-mn1);
      float ex0 = __expf(a0-mn0), ex1 = __expf(a1-mn1);
      den0 = den0*sc0 + ex0;       den1 = den1*sc1 + ex1;
      acc0 = acc0*sc0 + ex0*v0;    acc1 = acc1*sc1 + ex1*v1;
      m0 = mn0; m1 = mn1;
    }
  }
  if(i < i1){
    int sA = ssrc[i];
    const short* eA = es + (size_t)i*128;
    const short* kA = qk + (size_t)sA*512 + 128;
    body(bf2f(eA[lane]), bf2f(eA[lane+64]),
         bf2f(kA[lane]), bf2f(kA[lane+64]),
         bf2f(kA[lane+128]), bf2f(kA[lane+192]));
  }

  float o0 = acc0/(den0+1e-16f);
  float o1 = acc1/(den1+1e-16f);
  size_t base = (size_t)n*128;
  float a0 = xin[base+lane]    + o0 + bf2f(qrow[lane+384]);
  float a1 = xin[base+lane+64] + o1 + bf2f(qrow[lane+448]);
  xattn[base+lane] = a0; xattn[base+lane+64] = a1;
  float s  = allsum64(a0+a1);
  float s2 = allsum64(a0*a0 + a1*a1);
  float mean = s * (1.f/128.f);
  float var  = s2 * (1.f/128.f) - mean*mean;
  float rs = rsqrtf(var + 1e-5f);
  hf[base+lane]    = (a0-mean)*rs*g[lane]    + b[lane];
  hf[base+lane+64] = (a1-mean)*rs*g[lane+64] + b[lane+64];
}

// ---------------- xn = LN(x_new) with eu_ln -> bf16 ----------------
__global__ __launch_bounds__(256) void k_xn(
    const float* __restrict__ xnew, const float* __restrict__ g,
    const float* __restrict__ b, short* __restrict__ xn){
  int node = blockIdx.x*4 + (threadIdx.x>>6);
  int lane = threadIdx.x & 63;
  if(node >= N_NODES) return;
  size_t base = (size_t)node*D;
  float a0 = xnew[base+lane];
  float a1 = xnew[base+lane+64];
  float s  = allsum64(a0+a1);
  float s2 = allsum64(a0*a0 + a1*a1);
  float mean = s * (1.f/128.f);
  float var  = s2 * (1.f/128.f) - mean*mean;
  float rs = rsqrtf(var + 1e-5f);
  xn[base+lane]    = bfs((a0-mean)*rs*g[lane]    + b[lane]);
  xn[base+lane+64] = bfs((a1-mean)*rs*g[lane+64] + b[lane+64]);
}

// ---------------- EdgeUpdate via MFMA: 32 edges/wave (B-fragment reuse x2) ----------------
__global__ __launch_bounds__(256) void k_edge_mfma4(
    const int* __restrict__ src, const int* __restrict__ dst,
    const short* __restrict__ xnb, const float* __restrict__ ea,
    const short* __restrict__ Wmp, const float* __restrict__ bm,
    const float* __restrict__ eg, const float* __restrict__ ebv,
    float* __restrict__ out){
  const int tid = threadIdx.x, lane = tid & 63, wid = tid >> 6;
  const int l16 = lane & 15, lg = lane >> 4;
  const size_t e0 = (size_t)blockIdx.x*128 + wid*32;
  const int ko = lg*8;
  int sI[2], dI[2];
  sI[0] = src[e0+l16];    dI[0] = dst[e0+l16];
  sI[1] = src[e0+16+l16]; dI[1] = dst[e0+16+l16];
  f32x4 acc[8][2] = {};
  const short8* Bg = ((const short8*)Wmp) + lane;

#pragma unroll
  for(int kc=0; kc<10; kc++){
    short8 a[2];
#pragma unroll
    for(int mi=0;mi<2;mi++){
      if(kc < 8){
        int node = (kc < 4) ? sI[mi] : dI[mi];
        a[mi] = *(const short8*)(xnb + (size_t)node*128 + (kc&3)*32 + ko);
      } else {
        const float* ap = ea + (e0 + mi*16 + l16)*64 + (kc-8)*32 + ko;
        float4 f0 = *(const float4*)ap;
        float4 f1 = *(const float4*)(ap+4);
        a[mi][0]=bfs(f0.x); a[mi][1]=bfs(f0.y); a[mi][2]=bfs(f0.z); a[mi][3]=bfs(f0.w);
        a[mi][4]=bfs(f1.x); a[mi][5]=bfs(f1.y); a[mi][6]=bfs(f1.z); a[mi][7]=bfs(f1.w);
      }
    }
#pragma unroll
    for(int cf=0;cf<8;cf++){
      short8 b = Bg[(kc*8+cf)*64];
      acc[cf][0] = __builtin_amdgcn_mfma_f32_16x16x32_bf16(a[0], b, acc[cf][0], 0, 0, 0);
      acc[cf][1] = __builtin_amdgcn_mfma_f32_16x16x32_bf16(a[1], b, acc[cf][1], 0, 0, 0);
    }
  }

  float bmd[4], bmg[4], egc[4], ebc[4];
#pragma unroll
  for(int cf=0;cf<4;cf++){
    int col = cf*16 + l16;
    bmd[cf] = bm[col];
    bmg[cf] = bm[64+col];
    egc[cf] = eg[col];
    ebc[cf] = ebv[col];
  }
#pragma unroll
  for(int mi=0;mi<2;mi++){
#pragma unroll
    for(int r=0;r<4;r++){
      size_t erow = e0 + mi*16 + lg*4 + r;
      float u[4];
      float s1 = 0.f, s2 = 0.f;
#pragma unroll
      for(int cf=0;cf<4;cf++){
        float dlt = fmaxf(0.f, acc[cf][mi][r]   + bmd[cf]);
        float gt  = fmaxf(0.f, acc[cf+4][mi][r] + bmg[cf]);
        float uu = ea[erow*64 + cf*16 + l16] + dlt / (1.f + expf(-gt));
        u[cf] = uu; s1 += uu; s2 += uu*uu;
      }
#pragma unroll
      for(int off=1; off<16; off<<=1){
        s1 += __shfl_xor(s1, off, 64);
        s2 += __shfl_xor(s2, off, 64);
      }
      float mean = s1 * (1.f/64.f);
      float var  = s2 * (1.f/64.f) - mean*mean;
      float rs = rsqrtf(var + 1e-5f);
#pragma unroll
      for(int cf=0;cf<4;cf++)
        out[erow*64 + cf*16 + l16] = (u[cf]-mean)*rs*egc[cf] + ebc[cf];
    }
  }
}

extern "C" void kernel_launch(void* const* d_in, const int* in_sizes, int n_in,
                              void* d_out, int out_size, void* d_ws, size_t ws_size,
                              hipStream_t stream){
  const float* x       = (const float*)d_in[0];
  const int*   eidx    = (const int*)d_in[1];
  const float* eattr   = (const float*)d_in[2];
  const float* deg_emb = (const float*)d_in[3];
  const float* ln_g = (const float*)d_in[4];
  const float* ln_b = (const float*)d_in[5];
  const float* Wq = (const float*)d_in[6];  const float* bq = (const float*)d_in[7];
  const float* Wk = (const float*)d_in[8];  const float* bk = (const float*)d_in[9];
  const float* Wv = (const float*)d_in[10]; const float* bv = (const float*)d_in[11];
  const float* We = (const float*)d_in[12]; const float* be = (const float*)d_in[13];
  const float* Ws = (const float*)d_in[14]; const float* bs = (const float*)d_in[15];
  const float* W1 = (const float*)d_in[16]; const float* b1 = (const float*)d_in[17];
  const float* W2 = (const float*)d_in[18]; const float* b2 = (const float*)d_in[19];
  const float* eug = (const float*)d_in[20]; const float* eub = (const float*)d_in[21];
  const float* Wm = (const float*)d_in[22]; const float* bm = (const float*)d_in[23];
  const float* eg = (const float*)d_in[24]; const float* eb = (const float*)d_in[25];
  (void)in_sizes; (void)n_in; (void)out_size; (void)ws_size;

  const int* src = eidx;
  const int* dst = eidx + N_EDGES;

  float* ws = (float*)d_ws;
  size_t o = 0;
  auto alloc = [&](size_t n){ size_t r = o; o += (n + 63) & ~(size_t)63; return r; };
  size_t o_deg   = alloc(N_NODES);                 // int, memset
  size_t o_hist  = alloc(N_NODES);                 // int, memset
  size_t zero_f  = o;
  size_t o_rows  = alloc(N_NODES+1);               // int
  size_t o_cur   = alloc(N_NODES);                 // int
  size_t o_perm  = alloc(N_EDGES);                 // int
  size_t o_ssrc  = alloc(N_EDGES);                 // int
  size_t o_attn  = alloc((size_t)N_NODES*D);       // x_attn f32
  size_t o_xin   = alloc((size_t)N_NODES*D);       // x_in f32; xn(bf16) reuses later
  size_t o_h     = alloc((size_t)N_NODES*D);       // h -> hf
  size_t o_qkv16 = alloc((size_t)N_NODES*256);     // qkvs bf16 [N,512]; t1 reuses
  size_t o_wcat  = alloc((size_t)D*4*D);
  size_t o_bcat  = alloc(4*D);
  size_t o_wqp   = alloc((size_t)128*512/2);
  size_t o_w1p   = alloc((size_t)128*512/2);
  size_t o_w2p   = alloc((size_t)512*128/2);
  size_t o_wmp   = alloc((size_t)320*128/2);
  size_t o_wep   = alloc((size_t)64*128/2);

  float* xnew_out = (float*)d_out;                          // [N,128]
  float* ea_out   = xnew_out + (size_t)N_NODES*D;           // [E,64]
  __hip_bfloat16* es = (__hip_bfloat16*)ea_out;             // sorted e-proj staging

  hipMemsetAsync(d_ws, 0, zero_f*sizeof(float), stream);

  k_deg<<<(N_EDGES+255)/256, 256, 0, stream>>>(src, dst, (int*)(ws+o_deg),
                                               (int*)(ws+o_hist));
  k_scan<<<1, 1024, 0, stream>>>((int*)(ws+o_hist), (int*)(ws+o_rows),
                                 (int*)(ws+o_cur));
  k_scatter<<<(N_EDGES+255)/256, 256, 0, stream>>>(src, dst, (int*)(ws+o_cur),
                                                   (int*)(ws+o_perm),
                                                   (int*)(ws+o_ssrc));
  k_node_prep<<<N_NODES/4, 256, 0, stream>>>(x, (int*)(ws+o_deg), deg_emb, ln_g, ln_b,
                                             ws+o_xin, ws+o_h);
  k_pack<<<(D*4*D + 4*D + 255)/256, 256, 0, stream>>>(Wq,Wk,Wv,Ws, bq,bk,bv,bs,
                                                      ws+o_wcat, ws+o_bcat);
  k_packWN<<<256, 256, 0, stream>>>(ws+o_wcat, (short*)(ws+o_wqp), 128, 512);
  k_packWN<<<256, 256, 0, stream>>>(W1, (short*)(ws+o_w1p), 128, 512);
  k_packWN<<<256, 256, 0, stream>>>(W2, (short*)(ws+o_w2p), 512, 128);
  k_packWN<<<160, 256, 0, stream>>>(Wm, (short*)(ws+o_wmp), 320, 128);
  k_packWN<<<32,  256, 0, stream>>>(We, (short*)(ws+o_wep), 64, 128);
  {
    dim3 g((N_NODES+63)/64, 4);    // qkvs = bf16(h @ Wcat + bcat)
    k_gemm_mfma<0,false,__hip_bfloat16,float><<<g,256,0,stream>>>(
        ws+o_h, (const short*)(ws+o_wqp), ws+o_bcat, nullptr,
        (__hip_bfloat16*)(ws+o_qkv16), N_NODES, 128, 512);
  }
  k_eproj_sorted<<<N_EDGES/64, 256, 0, stream>>>(eattr, (const int*)(ws+o_perm),
                                                 (const short*)(ws+o_wep), be, es);
  k_attn_fused2<<<(N_NODES+3)/4, 256, 0, stream>>>((const int*)(ws+o_ssrc),
                                                   (int*)(ws+o_rows),
                                                   (const short*)(ws+o_qkv16),
                                                   (const short*)es,
                                                   ws+o_xin, ln_g, ln_b,
                                                   ws+o_attn, ws+o_h);
  {
    dim3 g((N_NODES+63)/64, 4);    // t1 = bf16(gelu(hf @ W1 + b1)) -> qkv16 region
    k_gemm_mfma<1,false,__hip_bfloat16,float><<<g,256,0,stream>>>(
        ws+o_h, (const short*)(ws+o_w1p), b1, nullptr,
        (__hip_bfloat16*)(ws+o_qkv16), N_NODES, 128, 512);
  }
  {
    dim3 g((N_NODES+63)/64, 1);    // x_new = t1 @ W2 + b2 + x_attn -> d_out
    k_gemm_mfma<0,true,float,short><<<g,256,0,stream>>>(
        (const short*)(ws+o_qkv16), (const short*)(ws+o_w2p), b2, ws+o_attn,
        xnew_out, N_NODES, 512, 128);
  }
  k_xn<<<N_NODES/4, 256, 0, stream>>>(xnew_out, eug, eub, (short*)(ws+o_xin));
  k_edge_mfma4<<<N_EDGES/128, 256, 0, stream>>>(src, dst, (const short*)(ws+o_xin),
                                                eattr, (const short*)(ws+o_wmp), bm,
                                                eg, eb, ea_out);
}